// Round 9
// baseline (2362.996 us; speedup 1.0000x reference)
//
#include <hip/hip_runtime.h>
#include <cstddef>

#define NN 50000
#define NNP 50048   // NN padded to multiple of TE (node arrays in workspace)
#define NE 640000
#define NB 4
#define H  128
#define NL 4
#define TE 64    // rows per block for node/enc MFMA kernels
#define TEE 128  // edges per block for k_edge_mfma (32 edges/wave x 4 waves)

typedef unsigned int u32;
typedef unsigned short u16;   // raw bf16 (intermediates only; I/O is fp32)
typedef __attribute__((ext_vector_type(8))) short bf16x8;
typedef __attribute__((ext_vector_type(4))) float f32x4;

__device__ __forceinline__ float bf2f(u16 s) {
    union { u32 u; float f; } v; v.u = ((u32)s) << 16; return v.f;
}
__device__ __forceinline__ u16 f2bf(float f) {
    union { float f; u32 u; } v; v.f = f;
    u32 u = v.u;
    u += 0x7FFF + ((u >> 16) & 1);   // RNE
    return (u16)(u >> 16);
}
__device__ __forceinline__ void unpack8(uint4 raw, float* d) {
    d[0] = bf2f(raw.x & 0xFFFF); d[1] = bf2f(raw.x >> 16);
    d[2] = bf2f(raw.y & 0xFFFF); d[3] = bf2f(raw.y >> 16);
    d[4] = bf2f(raw.z & 0xFFFF); d[5] = bf2f(raw.z >> 16);
    d[6] = bf2f(raw.w & 0xFFFF); d[7] = bf2f(raw.w >> 16);
}
__device__ __forceinline__ uint4 pack8(const float* s) {
    uint4 pk;
    pk.x = (u32)f2bf(s[0]) | ((u32)f2bf(s[1]) << 16);
    pk.y = (u32)f2bf(s[2]) | ((u32)f2bf(s[3]) << 16);
    pk.z = (u32)f2bf(s[4]) | ((u32)f2bf(s[5]) << 16);
    pk.w = (u32)f2bf(s[6]) | ((u32)f2bf(s[7]) << 16);
    return pk;
}
// fp32 row-slice (8 floats, 16B-aligned) -> bf16x8 A-fragment
__device__ __forceinline__ bf16x8 ld_f32_bf8(const float* __restrict__ p) {
    const float4 a = *(const float4*)p;
    const float4 b = *(const float4*)(p + 4);
    bf16x8 r;
    r[0] = (short)f2bf(a.x); r[1] = (short)f2bf(a.y);
    r[2] = (short)f2bf(a.z); r[3] = (short)f2bf(a.w);
    r[4] = (short)f2bf(b.x); r[5] = (short)f2bf(b.y);
    r[6] = (short)f2bf(b.z); r[7] = (short)f2bf(b.w);
    return r;
}

// ---------------------------------------------------------------------------
__global__ __launch_bounds__(256) void k_zero(float* __restrict__ p, int n4) {
    const int i = blockIdx.x * 256 + threadIdx.x;
    if (i < n4) ((float4*)p)[i] = make_float4(0.f, 0.f, 0.f, 0.f);
}

// ---------------------------------------------------------------------------
// Counting sort of edges by destination row.
// ---------------------------------------------------------------------------
__global__ __launch_bounds__(256) void k_hist(const int* __restrict__ rowi,
                                              u32* __restrict__ cnt) {
    const int i = blockIdx.x * 256 + threadIdx.x;
    if (i < NE) atomicAdd(&cnt[rowi[i]], 1u);
}

__global__ __launch_bounds__(1024) void k_scan(u32* __restrict__ cnt) {
    __shared__ u32 part[1024];
    const int t = threadIdx.x;
    const int CHUNK = (NN + 1023) / 1024;
    const int lo = t * CHUNK;
    const int hi = (lo + CHUNK < NN) ? lo + CHUNK : NN;
    u32 s = 0;
    for (int i = lo; i < hi; ++i) s += cnt[i];
    part[t] = s;
    __syncthreads();
    for (int ofs = 1; ofs < 1024; ofs <<= 1) {
        const u32 v = (t >= ofs) ? part[t - ofs] : 0u;
        __syncthreads();
        part[t] += v;
        __syncthreads();
    }
    u32 run = (t == 0) ? 0u : part[t - 1];   // exclusive prefix
    for (int i = lo; i < hi; ++i) { const u32 c = cnt[i]; cnt[i] = run; run += c; }
}

__global__ __launch_bounds__(256) void k_scatter(const int* __restrict__ rowi,
                                                 const int* __restrict__ coli,
                                                 u32* __restrict__ off,
                                                 int* __restrict__ permS,
                                                 int* __restrict__ rowS,
                                                 int* __restrict__ colS) {
    const int i = blockIdx.x * 256 + threadIdx.x;
    if (i < NE) {
        const int r = rowi[i];
        const u32 p = atomicAdd(&off[r], 1u);
        permS[p] = i; rowS[p] = r; colS[p] = coli[i];
    }
}

// ---------------------------------------------------------------------------
// k_prep: weights -> bf16, transposed to [n][k] for contiguous MFMA B-frags.
// ---------------------------------------------------------------------------
__global__ __launch_bounds__(256) void k_prep(
    const float* __restrict__ pe_w1, const float* __restrict__ pe_w2,
    const float* __restrict__ pn_w1, const float* __restrict__ pn_w2,
    const float* __restrict__ ew2,   const float* __restrict__ nw2,
    const float* __restrict__ dw1,
    u16* __restrict__ W1t, u16* __restrict__ W2t,
    u16* __restrict__ WaT, u16* __restrict__ WbT,
    u16* __restrict__ Wn1aT, u16* __restrict__ Wn1bT, u16* __restrict__ Wn2T,
    u16* __restrict__ W2et, u16* __restrict__ W2nt, u16* __restrict__ W1dt) {
    const int li = blockIdx.x;
    const float* src; u16* dst;
    switch (blockIdx.y) {
        case 0: src = pe_w1 + ((size_t)li * 512 + 256) * H; dst = W1t  + (size_t)li * H * H; break;
        case 1: src = pe_w2 + (size_t)li * H * H;           dst = W2t  + (size_t)li * H * H; break;
        case 2: src = pe_w1 + (size_t)li * 512 * H;         dst = WaT  + (size_t)li * H * H; break;
        case 3: src = pe_w1 + ((size_t)li * 512 + 128) * H; dst = WbT  + (size_t)li * H * H; break;
        case 4: src = pn_w1 + (size_t)li * 384 * H;         dst = Wn1aT + (size_t)li * H * H; break;
        case 5: src = pn_w1 + ((size_t)li * 384 + 128) * H; dst = Wn1bT + (size_t)li * H * H; break;
        case 6: src = pn_w2 + (size_t)li * H * H;           dst = Wn2T + (size_t)li * H * H; break;
        default:
            if (li == 0)      { src = ew2; dst = W2et; }
            else if (li == 1) { src = nw2; dst = W2nt; }
            else if (li == 2) { src = dw1; dst = W1dt; }
            else return;
            break;
    }
    for (int idx = threadIdx.x; idx < H * H; idx += 256) {
        const int n = idx >> 7, k = idx & 127;
        dst[idx] = f2bf(src[(size_t)k * H + n]);
    }
}

// ---------------------------------------------------------------------------
// k_small (verified R13): u, x_cond, per-layer consts cbat/nbat.
// ---------------------------------------------------------------------------
__global__ __launch_bounds__(128) void k_small(
    const float* __restrict__ cond,
    const float* __restrict__ ecw1, const float* __restrict__ ecb1,
    const float* __restrict__ ecw2, const float* __restrict__ ecb2,
    const float* __restrict__ wv, const float* __restrict__ bv,
    const float* __restrict__ wo, const float* __restrict__ bo,
    const float* __restrict__ pe_w1, const float* __restrict__ pe_b1,
    const float* __restrict__ pn_w1, const float* __restrict__ pn_b1,
    float* __restrict__ cbat, float* __restrict__ nbat) {
    __shared__ float tmp[NB][H];
    __shared__ float uL[NB][H];
    __shared__ float xcL[NB][H];
    const int t = threadIdx.x;
    for (int b = 0; b < NB; ++b) {
        float a = ecb1[t];
        for (int k = 0; k < 10; ++k) a = fmaf(cond[b * 10 + k], ecw1[k * H + t], a);
        tmp[b][t] = fmaxf(a, 0.f);
    }
    __syncthreads();
    for (int b = 0; b < NB; ++b) {
        float a = ecb2[t];
        for (int k = 0; k < H; ++k) a = fmaf(tmp[b][k], ecw2[k * H + t], a);
        uL[b][t] = a;
    }
    __syncthreads();
    for (int b = 0; b < NB; ++b) {
        float a = bv[t];
        for (int k = 0; k < H; ++k) a = fmaf(uL[b][k], wv[k * H + t], a);
        tmp[b][t] = a;
    }
    __syncthreads();
    for (int b = 0; b < NB; ++b) {
        float a = bo[t];
        for (int k = 0; k < H; ++k) a = fmaf(tmp[b][k], wo[k * H + t], a);
        xcL[b][t] = a;
    }
    __syncthreads();
    for (int l = 0; l < NL; ++l) {
        const float* w1u = pe_w1 + ((size_t)l * 512 + 384) * H;
        for (int b = 0; b < NB; ++b) {
            float a = pe_b1[l * H + t];
            for (int k = 0; k < H; ++k) a = fmaf(uL[b][k], w1u[k * H + t], a);
            cbat[(l * NB + b) * H + t] = a;
        }
        const float* w1x = pn_w1 + ((size_t)l * 384 + 256) * H;
        for (int b = 0; b < NB; ++b) {
            float a = pn_b1[l * H + t];
            for (int k = 0; k < H; ++k) a = fmaf(xcL[b][k], w1x[k * H + t], a);
            nbat[(l * NB + b) * H + t] = a;
        }
    }
}

// ---------------------------------------------------------------------------
// k_enc_e_mfma: edge encoder, writes e in SORTED order (gather via permS).
// ---------------------------------------------------------------------------
__global__ __launch_bounds__(256) void k_enc_e_mfma(
    const float* __restrict__ ea,                         // [E,4]
    const int* __restrict__ permS,
    const float* __restrict__ w1, const float* __restrict__ b1,
    const u16* __restrict__ W2et, const float* __restrict__ b2,
    u16* __restrict__ e) {
    __shared__ float SI[TE][H + 4];
    const int t = threadIdx.x;
    const long long e0 = (long long)blockIdx.x * TE;
    const int w = t >> 6, l = t & 63;
    const int m16 = l & 15, g = l >> 4;
    const int row = w * 16 + m16;

    const int src = permS[e0 + row];
    const float4 av = *(const float4*)&ea[(size_t)src * 4];

    bf16x8 afrag[4];
#pragma unroll
    for (int ks = 0; ks < 4; ++ks) {
        const int c0 = ks * 32 + g * 8;
        float hv[8];
        {
            const float4 ba = *(const float4*)&b1[c0];
            const float4 bb = *(const float4*)&b1[c0 + 4];
            hv[0] = ba.x; hv[1] = ba.y; hv[2] = ba.z; hv[3] = ba.w;
            hv[4] = bb.x; hv[5] = bb.y; hv[6] = bb.z; hv[7] = bb.w;
        }
#pragma unroll
        for (int k = 0; k < 4; ++k) {
            const float s = (k == 0) ? av.x : (k == 1) ? av.y : (k == 2) ? av.z : av.w;
            const float4 wa = *(const float4*)&w1[k * H + c0];
            const float4 wb = *(const float4*)&w1[k * H + c0 + 4];
            hv[0] = fmaf(s, wa.x, hv[0]); hv[1] = fmaf(s, wa.y, hv[1]);
            hv[2] = fmaf(s, wa.z, hv[2]); hv[3] = fmaf(s, wa.w, hv[3]);
            hv[4] = fmaf(s, wb.x, hv[4]); hv[5] = fmaf(s, wb.y, hv[5]);
            hv[6] = fmaf(s, wb.z, hv[6]); hv[7] = fmaf(s, wb.w, hv[7]);
        }
#pragma unroll
        for (int j = 0; j < 8; ++j) afrag[ks][j] = (short)f2bf(fmaxf(hv[j], 0.f));
    }

    f32x4 acc[8];
#pragma unroll
    for (int nt = 0; nt < 8; ++nt) {
        const float bb = b2[nt * 16 + m16];
        acc[nt][0] = bb; acc[nt][1] = bb; acc[nt][2] = bb; acc[nt][3] = bb;
    }
#pragma unroll
    for (int ks = 0; ks < 4; ++ks) {
#pragma unroll
        for (int nt = 0; nt < 8; ++nt) {
            const bf16x8 bfr =
                *(const bf16x8*)&W2et[(size_t)(nt * 16 + m16) * H + ks * 32 + g * 8];
            acc[nt] = __builtin_amdgcn_mfma_f32_16x16x32_bf16(afrag[ks], bfr, acc[nt], 0, 0, 0);
        }
    }

#pragma unroll
    for (int nt = 0; nt < 8; ++nt)
#pragma unroll
        for (int j = 0; j < 4; ++j)
            SI[w * 16 + g * 4 + j][nt * 16 + m16] = acc[nt][j];
    __syncthreads();
    for (int u = t; u < TE * 16; u += 256) {
        const int j = u >> 4, c8 = (u & 15) * 8;
        *(uint4*)&e[(size_t)(e0 + j) * H + c8] = pack8(&SI[j][c8]);
    }
}

// ---------------------------------------------------------------------------
// k_enc_n_mfma: node encoder (verified R3).
// ---------------------------------------------------------------------------
__global__ __launch_bounds__(256) void k_enc_n_mfma(
    const float* __restrict__ x,                          // [N,12]
    const float* __restrict__ w1, const float* __restrict__ b1,
    const u16* __restrict__ W2nt, const float* __restrict__ b2,
    float* __restrict__ h) {
    __shared__ float SI[TE][H + 4];
    const int t = threadIdx.x;
    const long long n0 = (long long)blockIdx.x * TE;
    const int w = t >> 6, l = t & 63;
    const int m16 = l & 15, g = l >> 4;
    const int row = w * 16 + m16;
    const long long nr = (n0 + row < NN) ? (n0 + row) : (NN - 1);

    float av[12];
    {
        const float4 a0 = *(const float4*)&x[nr * 12];
        const float4 a1 = *(const float4*)&x[nr * 12 + 4];
        const float4 a2 = *(const float4*)&x[nr * 12 + 8];
        av[0] = a0.x; av[1] = a0.y; av[2] = a0.z; av[3] = a0.w;
        av[4] = a1.x; av[5] = a1.y; av[6] = a1.z; av[7] = a1.w;
        av[8] = a2.x; av[9] = a2.y; av[10] = a2.z; av[11] = a2.w;
    }

    bf16x8 afrag[4];
#pragma unroll
    for (int ks = 0; ks < 4; ++ks) {
        const int c0 = ks * 32 + g * 8;
        float hv[8];
        {
            const float4 ba = *(const float4*)&b1[c0];
            const float4 bb = *(const float4*)&b1[c0 + 4];
            hv[0] = ba.x; hv[1] = ba.y; hv[2] = ba.z; hv[3] = ba.w;
            hv[4] = bb.x; hv[5] = bb.y; hv[6] = bb.z; hv[7] = bb.w;
        }
#pragma unroll
        for (int k = 0; k < 12; ++k) {
            const float s = av[k];
            const float4 wa = *(const float4*)&w1[k * H + c0];
            const float4 wb = *(const float4*)&w1[k * H + c0 + 4];
            hv[0] = fmaf(s, wa.x, hv[0]); hv[1] = fmaf(s, wa.y, hv[1]);
            hv[2] = fmaf(s, wa.z, hv[2]); hv[3] = fmaf(s, wa.w, hv[3]);
            hv[4] = fmaf(s, wb.x, hv[4]); hv[5] = fmaf(s, wb.y, hv[5]);
            hv[6] = fmaf(s, wb.z, hv[6]); hv[7] = fmaf(s, wb.w, hv[7]);
        }
#pragma unroll
        for (int j = 0; j < 8; ++j) afrag[ks][j] = (short)f2bf(fmaxf(hv[j], 0.f));
    }

    f32x4 acc[8];
#pragma unroll
    for (int nt = 0; nt < 8; ++nt) {
        const float bb = b2[nt * 16 + m16];
        acc[nt][0] = bb; acc[nt][1] = bb; acc[nt][2] = bb; acc[nt][3] = bb;
    }
#pragma unroll
    for (int ks = 0; ks < 4; ++ks) {
#pragma unroll
        for (int nt = 0; nt < 8; ++nt) {
            const bf16x8 bfr =
                *(const bf16x8*)&W2nt[(size_t)(nt * 16 + m16) * H + ks * 32 + g * 8];
            acc[nt] = __builtin_amdgcn_mfma_f32_16x16x32_bf16(afrag[ks], bfr, acc[nt], 0, 0, 0);
        }
    }

#pragma unroll
    for (int nt = 0; nt < 8; ++nt)
#pragma unroll
        for (int j = 0; j < 4; ++j)
            SI[w * 16 + g * 4 + j][nt * 16 + m16] = acc[nt][j];
    __syncthreads();
    for (int u = t; u < TE * H / 4; u += 256) {
        const int j = u >> 5, c4 = (u & 31) * 4;
        *(float4*)&h[(size_t)(n0 + j) * H + c4] = *(const float4*)&SI[j][c4];
    }
}

// ---------------------------------------------------------------------------
// k_gemm_dual_mfma (verified R8): hA = h@Wa + cbat[batch] (folded), hB = h@Wb.
// ---------------------------------------------------------------------------
__global__ __launch_bounds__(256) void k_gemm_dual_mfma(
    const float* __restrict__ h,
    const u16* __restrict__ WaT, const u16* __restrict__ WbT,
    const float* __restrict__ cbatl, const int* __restrict__ batch,
    u16* __restrict__ Ca, u16* __restrict__ Cb) {
    __shared__ u16 SI[TE][H + 8];
    __shared__ float CB[NB][H];
    __shared__ int bL[TE];
    const int t = threadIdx.x;
    const long long n0 = (long long)blockIdx.x * TE;
    const int w = t >> 6, l = t & 63;
    const int m16 = l & 15, g = l >> 4;
    const int row = w * 16 + m16;

    if (t < TE) {
        const long long n = n0 + t;
        bL[t] = batch[n < NN ? n : (NN - 1)];
    }
    for (int i = t; i < NB * H; i += 256) ((float*)CB)[i] = cbatl[i];

    bf16x8 afrag[4];
    {
        const float* hp = h + (size_t)(n0 + row) * H + g * 8;
#pragma unroll
        for (int ks = 0; ks < 4; ++ks) afrag[ks] = ld_f32_bf8(hp + ks * 32);
    }
    __syncthreads();   // bL / CB visible

    f32x4 accA[8], accB[8];
#pragma unroll
    for (int nt = 0; nt < 8; ++nt) {
#pragma unroll
        for (int j = 0; j < 4; ++j)
            accA[nt][j] = CB[bL[w * 16 + g * 4 + j]][nt * 16 + m16];
        accB[nt][0] = 0.f; accB[nt][1] = 0.f; accB[nt][2] = 0.f; accB[nt][3] = 0.f;
    }
#pragma unroll
    for (int ks = 0; ks < 4; ++ks) {
#pragma unroll
        for (int nt = 0; nt < 8; ++nt) {
            const size_t off = (size_t)(nt * 16 + m16) * H + ks * 32 + g * 8;
            const bf16x8 ba = *(const bf16x8*)&WaT[off];
            const bf16x8 bb = *(const bf16x8*)&WbT[off];
            accA[nt] = __builtin_amdgcn_mfma_f32_16x16x32_bf16(afrag[ks], ba, accA[nt], 0, 0, 0);
            accB[nt] = __builtin_amdgcn_mfma_f32_16x16x32_bf16(afrag[ks], bb, accB[nt], 0, 0, 0);
        }
    }

#pragma unroll
    for (int s = 0; s < 2; ++s) {
        __syncthreads();   // protect SI reuse across the two stores
#pragma unroll
        for (int nt = 0; nt < 8; ++nt)
#pragma unroll
            for (int j = 0; j < 4; ++j)
                SI[w * 16 + g * 4 + j][nt * 16 + m16] =
                    f2bf(s ? accB[nt][j] : accA[nt][j]);
        __syncthreads();
        u16* C = s ? Cb : Ca;
        for (int u = t; u < TE * 16; u += 256) {
            const int j = u >> 4, c8 = (u & 15) * 8;
            *(uint4*)&C[(size_t)(n0 + j) * H + c8] = *(const uint4*)&SI[j][c8];
        }
    }
}

// ---------------------------------------------------------------------------
// k_edge_mfma (R9): TEE=128, 4 INDEPENDENT waves x 32 edges.  ZERO barriers:
// each wave stages ITS OWN 32 edges' init into its own SI rows, reads them
// back (same-wave DS ordering — harness-verified pattern since R6), GEMMs,
// and writes its own e rows.  Accumulator pair reused across GEMM1/GEMM2.
// ---------------------------------------------------------------------------
template <bool WRITE_E>
__global__ __launch_bounds__(256, 2) void k_edge_mfma(
    const u16* __restrict__ hA, const u16* __restrict__ hB,
    const u16* __restrict__ W1t, const u16* __restrict__ W2t,
    const float* __restrict__ b2,
    const int* __restrict__ rowS, const int* __restrict__ colS,
    u16* __restrict__ e, float* __restrict__ agg) {
    __shared__ u16 SI[TEE][H + 8];       // bf16; wave w owns rows [w*32,w*32+32)
    const int t = threadIdx.x;
    const long long e0 = (long long)blockIdx.x * TEE;
    const int w = t >> 6, l = t & 63;
    const int m16 = l & 15, g = l >> 4;

    // e A-fragments for both m-tiles — 8 x 16B, issued up front
    bf16x8 af0[4], af1[4];
    {
        const u16* ep0 = e + (size_t)(e0 + w * 32 + m16) * H + g * 8;
        const u16* ep1 = ep0 + 16 * H;
#pragma unroll
        for (int ks = 0; ks < 4; ++ks) {
            af0[ks] = *(const bf16x8*)(ep0 + ks * 32);
            af1[ks] = *(const bf16x8*)(ep1 + ks * 32);
        }
    }

    // wave-local stage: init = hA'[row] + hB[col] for this wave's 32 edges.
    // lane handles 8 chunks: u = l + it*64 -> j = u>>4 (0..31), c8 = (u&15)*8
    {
        int rj[8], cj[8];
#pragma unroll
        for (int it = 0; it < 8; ++it) {
            const int j = (l + it * 64) >> 4;
            rj[it] = rowS[e0 + w * 32 + j];
            cj[it] = colS[e0 + w * 32 + j];
        }
#pragma unroll
        for (int it = 0; it < 8; ++it) {
            const int u = l + it * 64;
            const int j = u >> 4, c8 = (u & 15) * 8;
            float va[8], vb[8], sm[8];
            unpack8(*(const uint4*)&hA[(size_t)rj[it] * H + c8], va);
            unpack8(*(const uint4*)&hB[(size_t)cj[it] * H + c8], vb);
#pragma unroll
            for (int q = 0; q < 8; ++q) sm[q] = va[q] + vb[q];
            *(uint4*)&SI[w * 32 + j][c8] = pack8(sm);
        }
    }
    // NO barrier: same-wave ds_write -> ds_read ordering suffices.

    // ---- GEMM1: acc = init + e @ W1c (B-frag shared across both m-tiles) ----
    f32x4 acc0[8], acc1[8];
#pragma unroll
    for (int nt = 0; nt < 8; ++nt) {
#pragma unroll
        for (int j = 0; j < 4; ++j) {
            acc0[nt][j] = bf2f(SI[w * 32 + g * 4 + j][nt * 16 + m16]);
            acc1[nt][j] = bf2f(SI[w * 32 + 16 + g * 4 + j][nt * 16 + m16]);
        }
    }
#pragma unroll
    for (int ks = 0; ks < 4; ++ks) {
#pragma unroll
        for (int nt = 0; nt < 8; ++nt) {
            const bf16x8 bfr =
                *(const bf16x8*)&W1t[(size_t)(nt * 16 + m16) * H + ks * 32 + g * 8];
            acc0[nt] = __builtin_amdgcn_mfma_f32_16x16x32_bf16(af0[ks], bfr, acc0[nt], 0, 0, 0);
            acc1[nt] = __builtin_amdgcn_mfma_f32_16x16x32_bf16(af1[ks], bfr, acc1[nt], 0, 0, 0);
        }
    }

    // hidden = relu -> SI (wave-own rows; same-wave DS ordering, no barrier)
#pragma unroll
    for (int nt = 0; nt < 8; ++nt)
#pragma unroll
        for (int j = 0; j < 4; ++j) {
            SI[w * 32 + g * 4 + j][nt * 16 + m16]      = f2bf(fmaxf(acc0[nt][j], 0.f));
            SI[w * 32 + 16 + g * 4 + j][nt * 16 + m16] = f2bf(fmaxf(acc1[nt][j], 0.f));
        }

    // ---- GEMM2: REUSE acc0/acc1 (re-init with b2) ----
#pragma unroll
    for (int nt = 0; nt < 8; ++nt) {
        const float bb = b2[nt * 16 + m16];
        acc0[nt][0] = bb; acc0[nt][1] = bb; acc0[nt][2] = bb; acc0[nt][3] = bb;
        acc1[nt][0] = bb; acc1[nt][1] = bb; acc1[nt][2] = bb; acc1[nt][3] = bb;
    }
#pragma unroll
    for (int ks = 0; ks < 4; ++ks) {
        const bf16x8 a20 = *(const bf16x8*)&SI[w * 32 + m16][ks * 32 + g * 8];
        const bf16x8 a21 = *(const bf16x8*)&SI[w * 32 + 16 + m16][ks * 32 + g * 8];
#pragma unroll
        for (int nt = 0; nt < 8; ++nt) {
            const bf16x8 bfr =
                *(const bf16x8*)&W2t[(size_t)(nt * 16 + m16) * H + ks * 32 + g * 8];
            acc0[nt] = __builtin_amdgcn_mfma_f32_16x16x32_bf16(a20, bfr, acc0[nt], 0, 0, 0);
            acc1[nt] = __builtin_amdgcn_mfma_f32_16x16x32_bf16(a21, bfr, acc1[nt], 0, 0, 0);
        }
    }

    // agg: f32 register atomics, one merge chain over the 8 sorted rows/lane
    {
        int r[8];
#pragma unroll
        for (int j = 0; j < 4; ++j) {
            r[j]     = rowS[e0 + w * 32 + g * 4 + j];
            r[4 + j] = rowS[e0 + w * 32 + 16 + g * 4 + j];
        }
#pragma unroll
        for (int nt = 0; nt < 8; ++nt) {
            const int c = nt * 16 + m16;
            float v[8];
#pragma unroll
            for (int j = 0; j < 4; ++j) { v[j] = acc0[nt][j]; v[4 + j] = acc1[nt][j]; }
            float s = v[0];
            int prev = r[0];
#pragma unroll
            for (int j = 1; j < 8; ++j) {
                if (r[j] == prev) s += v[j];
                else { atomicAdd(&agg[(size_t)prev * H + c], s); s = v[j]; prev = r[j]; }
            }
            atomicAdd(&agg[(size_t)prev * H + c], s);
        }
    }

    if (WRITE_E) {
        // stage output to wave-own SI rows, then wave-local packed stores
#pragma unroll
        for (int nt = 0; nt < 8; ++nt)
#pragma unroll
            for (int j = 0; j < 4; ++j) {
                SI[w * 32 + g * 4 + j][nt * 16 + m16]      = f2bf(acc0[nt][j]);
                SI[w * 32 + 16 + g * 4 + j][nt * 16 + m16] = f2bf(acc1[nt][j]);
            }
        // NO barrier: wave writes its own 32 edges
#pragma unroll
        for (int it = 0; it < 8; ++it) {
            const int u = l + it * 64;
            const int j = u >> 4, c8 = (u & 15) * 8;
            *(uint4*)&e[(size_t)(e0 + w * 32 + j) * H + c8] = *(const uint4*)&SI[w * 32 + j][c8];
        }
    }
}

// ---------------------------------------------------------------------------
// k_node_mfma (verified R3): h += relu(h@Wn1a + agg@Wn1b + nbat[batch])@Wn2+bn2
// ---------------------------------------------------------------------------
__global__ __launch_bounds__(256) void k_node_mfma(
    const u16* __restrict__ Wn1aT, const u16* __restrict__ Wn1bT,
    const u16* __restrict__ Wn2T, const float* __restrict__ bn2,
    const float* __restrict__ nbatl, const int* __restrict__ batch,
    const float* __restrict__ agg, float* __restrict__ h) {
    __shared__ float SI[TE][H + 4];
    __shared__ float NBl[NB][H];
    __shared__ int bL[TE];
    const int t = threadIdx.x;
    const long long n0 = (long long)blockIdx.x * TE;
    if (t < TE) {
        const long long n = n0 + t;
        bL[t] = batch[n < NN ? n : (NN - 1)];
    }
    for (int i = t; i < NB * H; i += 256) ((float*)NBl)[i] = nbatl[i];

    const int w = t >> 6, l = t & 63;
    const int m16 = l & 15, g = l >> 4;
    const int row = w * 16 + m16;

    bf16x8 afrag[4];
    {
        const float* hp = h + (size_t)(n0 + row) * H + g * 8;
#pragma unroll
        for (int ks = 0; ks < 4; ++ks) afrag[ks] = ld_f32_bf8(hp + ks * 32);
    }
    __syncthreads();   // bL / NBl visible

    f32x4 acc[8];
#pragma unroll
    for (int nt = 0; nt < 8; ++nt)
#pragma unroll
        for (int j = 0; j < 4; ++j)
            acc[nt][j] = NBl[bL[w * 16 + g * 4 + j]][nt * 16 + m16];

#pragma unroll
    for (int ks = 0; ks < 4; ++ks)
#pragma unroll
        for (int nt = 0; nt < 8; ++nt) {
            const bf16x8 bfr =
                *(const bf16x8*)&Wn1aT[(size_t)(nt * 16 + m16) * H + ks * 32 + g * 8];
            acc[nt] = __builtin_amdgcn_mfma_f32_16x16x32_bf16(afrag[ks], bfr, acc[nt], 0, 0, 0);
        }

    {
        const float* ap = agg + (size_t)(n0 + row) * H + g * 8;
#pragma unroll
        for (int ks = 0; ks < 4; ++ks) afrag[ks] = ld_f32_bf8(ap + ks * 32);
    }
#pragma unroll
    for (int ks = 0; ks < 4; ++ks)
#pragma unroll
        for (int nt = 0; nt < 8; ++nt) {
            const bf16x8 bfr =
                *(const bf16x8*)&Wn1bT[(size_t)(nt * 16 + m16) * H + ks * 32 + g * 8];
            acc[nt] = __builtin_amdgcn_mfma_f32_16x16x32_bf16(afrag[ks], bfr, acc[nt], 0, 0, 0);
        }

    // hidden = relu(acc) -> SI
#pragma unroll
    for (int nt = 0; nt < 8; ++nt)
#pragma unroll
        for (int j = 0; j < 4; ++j)
            SI[w * 16 + g * 4 + j][nt * 16 + m16] = fmaxf(acc[nt][j], 0.f);
    __syncthreads();

    f32x4 acc2[8];
#pragma unroll
    for (int nt = 0; nt < 8; ++nt) {
        const float bb = bn2[nt * 16 + m16];
        acc2[nt][0] = bb; acc2[nt][1] = bb; acc2[nt][2] = bb; acc2[nt][3] = bb;
    }
#pragma unroll
    for (int ks = 0; ks < 4; ++ks) {
        bf16x8 a2;
        const float* hp = &SI[w * 16 + m16][ks * 32 + g * 8];
#pragma unroll
        for (int j = 0; j < 8; ++j) a2[j] = (short)f2bf(hp[j]);
#pragma unroll
        for (int nt = 0; nt < 8; ++nt) {
            const bf16x8 bfr =
                *(const bf16x8*)&Wn2T[(size_t)(nt * 16 + m16) * H + ks * 32 + g * 8];
            acc2[nt] = __builtin_amdgcn_mfma_f32_16x16x32_bf16(a2, bfr, acc2[nt], 0, 0, 0);
        }
    }
    __syncthreads();   // hidden reads done before overwrite

#pragma unroll
    for (int nt = 0; nt < 8; ++nt)
#pragma unroll
        for (int j = 0; j < 4; ++j)
            SI[w * 16 + g * 4 + j][nt * 16 + m16] = acc2[nt][j];
    __syncthreads();

    // h += (coalesced float4 RMW)
    for (int u = t; u < TE * H / 4; u += 256) {
        const int j = u >> 5, c4 = (u & 31) * 4;
        float4 hv = *(const float4*)&h[(size_t)(n0 + j) * H + c4];
        const float4 sv = *(const float4*)&SI[j][c4];
        hv.x += sv.x; hv.y += sv.y; hv.z += sv.z; hv.w += sv.w;
        *(float4*)&h[(size_t)(n0 + j) * H + c4] = hv;
    }
}

// ---------------------------------------------------------------------------
// k_dec_mfma: decoder.  Layer 1 (H x H) via MFMA; 3-col layer 2 via VALU.
// ---------------------------------------------------------------------------
__global__ __launch_bounds__(256) void k_dec_mfma(
    const float* __restrict__ h,
    const u16* __restrict__ W1dt, const float* __restrict__ b1,
    const float* __restrict__ w2, const float* __restrict__ b2,
    float* __restrict__ out) {
    __shared__ float SI[TE][H + 4];
    const int t = threadIdx.x;
    const long long n0 = (long long)blockIdx.x * TE;
    const int w = t >> 6, l = t & 63;
    const int m16 = l & 15, g = l >> 4;
    const int row = w * 16 + m16;

    bf16x8 afrag[4];
    {
        const float* hp = h + (size_t)(n0 + row) * H + g * 8;
#pragma unroll
        for (int ks = 0; ks < 4; ++ks) afrag[ks] = ld_f32_bf8(hp + ks * 32);
    }

    f32x4 acc[8];
#pragma unroll
    for (int nt = 0; nt < 8; ++nt) {
        const float bb = b1[nt * 16 + m16];
        acc[nt][0] = bb; acc[nt][1] = bb; acc[nt][2] = bb; acc[nt][3] = bb;
    }
#pragma unroll
    for (int ks = 0; ks < 4; ++ks) {
#pragma unroll
        for (int nt = 0; nt < 8; ++nt) {
            const bf16x8 bfr =
                *(const bf16x8*)&W1dt[(size_t)(nt * 16 + m16) * H + ks * 32 + g * 8];
            acc[nt] = __builtin_amdgcn_mfma_f32_16x16x32_bf16(afrag[ks], bfr, acc[nt], 0, 0, 0);
        }
    }

    // hidden = relu -> SI
#pragma unroll
    for (int nt = 0; nt < 8; ++nt)
#pragma unroll
        for (int j = 0; j < 4; ++j)
            SI[w * 16 + g * 4 + j][nt * 16 + m16] = fmaxf(acc[nt][j], 0.f);
    __syncthreads();

    if (t < TE * 3) {
        const int n = t / 3, c = t - n * 3;
        if (n0 + n < NN) {
            float v = b2[c];
            for (int k = 0; k < H; ++k) v = fmaf(SI[n][k], w2[k * 3 + c], v);
            out[(size_t)(n0 + n) * 3 + c] = v;
        }
    }
}

// ---------------------------------------------------------------------------
extern "C" void kernel_launch(void* const* d_in, const int* in_sizes, int n_in,
                              void* d_out, int out_size, void* d_ws, size_t ws_size,
                              hipStream_t stream) {
    const float* x          = (const float*)d_in[0];
    const int*   edge_index = (const int*)d_in[1];
    const float* edge_attr  = (const float*)d_in[2];
    const float* cond       = (const float*)d_in[3];
    const int*   batch      = (const int*)d_in[4];
    const float* enc_node_w1 = (const float*)d_in[5];
    const float* enc_node_b1 = (const float*)d_in[6];
    const float* enc_node_w2 = (const float*)d_in[7];
    const float* enc_node_b2 = (const float*)d_in[8];
    const float* enc_edge_w1 = (const float*)d_in[9];
    const float* enc_edge_b1 = (const float*)d_in[10];
    const float* enc_edge_w2 = (const float*)d_in[11];
    const float* enc_edge_b2 = (const float*)d_in[12];
    const float* enc_cond_w1 = (const float*)d_in[13];
    const float* enc_cond_b1 = (const float*)d_in[14];
    const float* enc_cond_w2 = (const float*)d_in[15];
    const float* enc_cond_b2 = (const float*)d_in[16];
    const float* attn_wv = (const float*)d_in[17];
    const float* attn_bv = (const float*)d_in[18];
    const float* attn_wo = (const float*)d_in[19];
    const float* attn_bo = (const float*)d_in[20];
    const float* pe_w1 = (const float*)d_in[21];
    const float* pe_b1 = (const float*)d_in[22];
    const float* pe_w2 = (const float*)d_in[23];
    const float* pe_b2 = (const float*)d_in[24];
    const float* pn_w1 = (const float*)d_in[25];
    const float* pn_b1 = (const float*)d_in[26];
    const float* pn_w2 = (const float*)d_in[27];
    const float* pn_b2 = (const float*)d_in[28];
    const float* dec_w1 = (const float*)d_in[29];
    const float* dec_b1 = (const float*)d_in[30];
    const float* dec_w2 = (const float*)d_in[31];
    const float* dec_b2 = (const float*)d_in[32];

    // workspace (~250 MB): node arrays padded to NNP rows
    u16*   e    = (u16*)d_ws;                                  // NE*H bf16
    float* h    = (float*)((char*)d_ws + (size_t)NE * H * 2);  // NNP*H f32
    float* agg  = h + (size_t)NNP * H;                         // NNP*H f32
    u16*   hA   = (u16*)(agg + (size_t)NNP * H);               // NNP*H bf16
    u16*   hB   = hA + (size_t)NNP * H;                        // NNP*H bf16
    float* cbat = (float*)(hB + (size_t)NNP * H);              // NL*NB*H f32
    float* nbat = cbat + NL * NB * H;                          // NL*NB*H f32
    u16*   W1t   = (u16*)(nbat + NL * NB * H);                 // NL*H*H bf16 each:
    u16*   W2t   = W1t  + (size_t)NL * H * H;
    u16*   WaT   = W2t  + (size_t)NL * H * H;
    u16*   WbT   = WaT  + (size_t)NL * H * H;
    u16*   Wn1aT = WbT  + (size_t)NL * H * H;
    u16*   Wn1bT = Wn1aT + (size_t)NL * H * H;
    u16*   Wn2T  = Wn1bT + (size_t)NL * H * H;
    u16*   W2et  = Wn2T + (size_t)NL * H * H;                  // H*H bf16
    u16*   W2nt  = W2et + (size_t)H * H;                       // H*H bf16
    u16*   W1dt  = W2nt + (size_t)H * H;                       // H*H bf16
    u32*   cnt   = (u32*)(W1dt + (size_t)H * H);               // NNP u32
    int*   permS = (int*)(cnt + NNP);                          // NE int
    int*   rowS  = permS + NE;                                 // NE int (sorted rows)
    int*   colS  = rowS + NE;                                  // NE int (sorted cols)

    const int* rowi = edge_index;
    const int* coli = edge_index + NE;
    float* out = (float*)d_out;

    // ---- counting sort of edges by row (once per launch) ----
    k_zero<<<(NNP / 4 + 255) / 256, 256, 0, stream>>>((float*)cnt, NNP / 4);
    k_hist<<<NE / 256, 256, 0, stream>>>(rowi, cnt);
    k_scan<<<1, 1024, 0, stream>>>(cnt);
    k_scatter<<<NE / 256, 256, 0, stream>>>(rowi, coli, cnt, permS, rowS, colS);

    k_prep<<<dim3(NL, 8), 256, 0, stream>>>(pe_w1, pe_w2, pn_w1, pn_w2,
                                            enc_edge_w2, enc_node_w2, dec_w1,
                                            W1t, W2t, WaT, WbT,
                                            Wn1aT, Wn1bT, Wn2T, W2et, W2nt, W1dt);
    k_small<<<1, 128, 0, stream>>>(cond, enc_cond_w1, enc_cond_b1, enc_cond_w2, enc_cond_b2,
                                   attn_wv, attn_bv, attn_wo, attn_bo,
                                   pe_w1, pe_b1, pn_w1, pn_b1, cbat, nbat);
    k_enc_n_mfma<<<NNP / TE, 256, 0, stream>>>(
        x, enc_node_w1, enc_node_b1, W2nt, enc_node_b2, h);
    k_enc_e_mfma<<<NE / TE, 256, 0, stream>>>(
        edge_attr, permS, enc_edge_w1, enc_edge_b1, W2et, enc_edge_b2, e);

    for (int l = 0; l < NL; ++l) {
        k_zero<<<(NNP * H / 4 + 255) / 256, 256, 0, stream>>>(agg, NNP * H / 4);
        k_gemm_dual_mfma<<<NNP / TE, 256, 0, stream>>>(
            h, WaT + (size_t)l * H * H, WbT + (size_t)l * H * H,
            cbat + l * NB * H, batch, hA, hB);
        if (l < NL - 1)
            k_edge_mfma<true><<<NE / TEE, 256, 0, stream>>>(
                hA, hB, W1t + (size_t)l * H * H, W2t + (size_t)l * H * H,
                pe_b2 + l * H, rowS, colS, e, agg);
        else
            k_edge_mfma<false><<<NE / TEE, 256, 0, stream>>>(
                hA, hB, W1t + (size_t)l * H * H, W2t + (size_t)l * H * H,
                pe_b2 + l * H, rowS, colS, e, agg);
        k_node_mfma<<<NNP / TE, 256, 0, stream>>>(
            Wn1aT + (size_t)l * H * H, Wn1bT + (size_t)l * H * H,
            Wn2T + (size_t)l * H * H, pn_b2 + l * H,
            nbat + l * NB * H, batch, agg, h);
    }
    k_dec_mfma<<<NNP / TE, 256, 0, stream>>>(h, W1dt, dec_b1, dec_w2, dec_b2, out);
}

// Round 10
// 2318.980 us; speedup vs baseline: 1.0190x; 1.0190x over previous
//
#include <hip/hip_runtime.h>
#include <cstddef>

#define NN 50000
#define NNP 50048   // NN padded to multiple of TE (node arrays in workspace)
#define NE 640000
#define NB 4
#define H  128
#define NL 4
#define TE 64    // rows per block for node/enc MFMA kernels
#define TEE 128  // edges per block for k_edge_mfma (32 edges/wave x 4 waves)

typedef unsigned int u32;
typedef unsigned short u16;   // raw bf16 (intermediates only; I/O is fp32)
typedef __attribute__((ext_vector_type(8))) short bf16x8;
typedef __attribute__((ext_vector_type(4))) float f32x4;

__device__ __forceinline__ float bf2f(u16 s) {
    union { u32 u; float f; } v; v.u = ((u32)s) << 16; return v.f;
}
__device__ __forceinline__ u16 f2bf(float f) {
    union { float f; u32 u; } v; v.f = f;
    u32 u = v.u;
    u += 0x7FFF + ((u >> 16) & 1);   // RNE
    return (u16)(u >> 16);
}
__device__ __forceinline__ void unpack8(uint4 raw, float* d) {
    d[0] = bf2f(raw.x & 0xFFFF); d[1] = bf2f(raw.x >> 16);
    d[2] = bf2f(raw.y & 0xFFFF); d[3] = bf2f(raw.y >> 16);
    d[4] = bf2f(raw.z & 0xFFFF); d[5] = bf2f(raw.z >> 16);
    d[6] = bf2f(raw.w & 0xFFFF); d[7] = bf2f(raw.w >> 16);
}
__device__ __forceinline__ uint4 pack8(const float* s) {
    uint4 pk;
    pk.x = (u32)f2bf(s[0]) | ((u32)f2bf(s[1]) << 16);
    pk.y = (u32)f2bf(s[2]) | ((u32)f2bf(s[3]) << 16);
    pk.z = (u32)f2bf(s[4]) | ((u32)f2bf(s[5]) << 16);
    pk.w = (u32)f2bf(s[6]) | ((u32)f2bf(s[7]) << 16);
    return pk;
}
// fp32 row-slice (8 floats, 16B-aligned) -> bf16x8 A-fragment
__device__ __forceinline__ bf16x8 ld_f32_bf8(const float* __restrict__ p) {
    const float4 a = *(const float4*)p;
    const float4 b = *(const float4*)(p + 4);
    bf16x8 r;
    r[0] = (short)f2bf(a.x); r[1] = (short)f2bf(a.y);
    r[2] = (short)f2bf(a.z); r[3] = (short)f2bf(a.w);
    r[4] = (short)f2bf(b.x); r[5] = (short)f2bf(b.y);
    r[6] = (short)f2bf(b.z); r[7] = (short)f2bf(b.w);
    return r;
}

// ---------------------------------------------------------------------------
__global__ __launch_bounds__(256) void k_zero(float* __restrict__ p, int n4) {
    const int i = blockIdx.x * 256 + threadIdx.x;
    if (i < n4) ((float4*)p)[i] = make_float4(0.f, 0.f, 0.f, 0.f);
}

// ---------------------------------------------------------------------------
// Counting sort of edges by destination row.
// ---------------------------------------------------------------------------
__global__ __launch_bounds__(256) void k_hist(const int* __restrict__ rowi,
                                              u32* __restrict__ cnt) {
    const int i = blockIdx.x * 256 + threadIdx.x;
    if (i < NE) atomicAdd(&cnt[rowi[i]], 1u);
}

__global__ __launch_bounds__(1024) void k_scan(u32* __restrict__ cnt) {
    __shared__ u32 part[1024];
    const int t = threadIdx.x;
    const int CHUNK = (NN + 1023) / 1024;
    const int lo = t * CHUNK;
    const int hi = (lo + CHUNK < NN) ? lo + CHUNK : NN;
    u32 s = 0;
    for (int i = lo; i < hi; ++i) s += cnt[i];
    part[t] = s;
    __syncthreads();
    for (int ofs = 1; ofs < 1024; ofs <<= 1) {
        const u32 v = (t >= ofs) ? part[t - ofs] : 0u;
        __syncthreads();
        part[t] += v;
        __syncthreads();
    }
    u32 run = (t == 0) ? 0u : part[t - 1];   // exclusive prefix
    for (int i = lo; i < hi; ++i) { const u32 c = cnt[i]; cnt[i] = run; run += c; }
}

__global__ __launch_bounds__(256) void k_scatter(const int* __restrict__ rowi,
                                                 const int* __restrict__ coli,
                                                 u32* __restrict__ off,
                                                 int* __restrict__ permS,
                                                 int* __restrict__ rowS,
                                                 int* __restrict__ colS) {
    const int i = blockIdx.x * 256 + threadIdx.x;
    if (i < NE) {
        const int r = rowi[i];
        const u32 p = atomicAdd(&off[r], 1u);
        permS[p] = i; rowS[p] = r; colS[p] = coli[i];
    }
}

// ---------------------------------------------------------------------------
// k_prep: weights -> bf16, transposed to [n][k] for contiguous MFMA B-frags.
// ---------------------------------------------------------------------------
__global__ __launch_bounds__(256) void k_prep(
    const float* __restrict__ pe_w1, const float* __restrict__ pe_w2,
    const float* __restrict__ pn_w1, const float* __restrict__ pn_w2,
    const float* __restrict__ ew2,   const float* __restrict__ nw2,
    const float* __restrict__ dw1,
    u16* __restrict__ W1t, u16* __restrict__ W2t,
    u16* __restrict__ WaT, u16* __restrict__ WbT,
    u16* __restrict__ Wn1aT, u16* __restrict__ Wn1bT, u16* __restrict__ Wn2T,
    u16* __restrict__ W2et, u16* __restrict__ W2nt, u16* __restrict__ W1dt) {
    const int li = blockIdx.x;
    const float* src; u16* dst;
    switch (blockIdx.y) {
        case 0: src = pe_w1 + ((size_t)li * 512 + 256) * H; dst = W1t  + (size_t)li * H * H; break;
        case 1: src = pe_w2 + (size_t)li * H * H;           dst = W2t  + (size_t)li * H * H; break;
        case 2: src = pe_w1 + (size_t)li * 512 * H;         dst = WaT  + (size_t)li * H * H; break;
        case 3: src = pe_w1 + ((size_t)li * 512 + 128) * H; dst = WbT  + (size_t)li * H * H; break;
        case 4: src = pn_w1 + (size_t)li * 384 * H;         dst = Wn1aT + (size_t)li * H * H; break;
        case 5: src = pn_w1 + ((size_t)li * 384 + 128) * H; dst = Wn1bT + (size_t)li * H * H; break;
        case 6: src = pn_w2 + (size_t)li * H * H;           dst = Wn2T + (size_t)li * H * H; break;
        default:
            if (li == 0)      { src = ew2; dst = W2et; }
            else if (li == 1) { src = nw2; dst = W2nt; }
            else if (li == 2) { src = dw1; dst = W1dt; }
            else return;
            break;
    }
    for (int idx = threadIdx.x; idx < H * H; idx += 256) {
        const int n = idx >> 7, k = idx & 127;
        dst[idx] = f2bf(src[(size_t)k * H + n]);
    }
}

// ---------------------------------------------------------------------------
// k_small (verified R13): u, x_cond, per-layer consts cbat/nbat.
// ---------------------------------------------------------------------------
__global__ __launch_bounds__(128) void k_small(
    const float* __restrict__ cond,
    const float* __restrict__ ecw1, const float* __restrict__ ecb1,
    const float* __restrict__ ecw2, const float* __restrict__ ecb2,
    const float* __restrict__ wv, const float* __restrict__ bv,
    const float* __restrict__ wo, const float* __restrict__ bo,
    const float* __restrict__ pe_w1, const float* __restrict__ pe_b1,
    const float* __restrict__ pn_w1, const float* __restrict__ pn_b1,
    float* __restrict__ cbat, float* __restrict__ nbat) {
    __shared__ float tmp[NB][H];
    __shared__ float uL[NB][H];
    __shared__ float xcL[NB][H];
    const int t = threadIdx.x;
    for (int b = 0; b < NB; ++b) {
        float a = ecb1[t];
        for (int k = 0; k < 10; ++k) a = fmaf(cond[b * 10 + k], ecw1[k * H + t], a);
        tmp[b][t] = fmaxf(a, 0.f);
    }
    __syncthreads();
    for (int b = 0; b < NB; ++b) {
        float a = ecb2[t];
        for (int k = 0; k < H; ++k) a = fmaf(tmp[b][k], ecw2[k * H + t], a);
        uL[b][t] = a;
    }
    __syncthreads();
    for (int b = 0; b < NB; ++b) {
        float a = bv[t];
        for (int k = 0; k < H; ++k) a = fmaf(uL[b][k], wv[k * H + t], a);
        tmp[b][t] = a;
    }
    __syncthreads();
    for (int b = 0; b < NB; ++b) {
        float a = bo[t];
        for (int k = 0; k < H; ++k) a = fmaf(tmp[b][k], wo[k * H + t], a);
        xcL[b][t] = a;
    }
    __syncthreads();
    for (int l = 0; l < NL; ++l) {
        const float* w1u = pe_w1 + ((size_t)l * 512 + 384) * H;
        for (int b = 0; b < NB; ++b) {
            float a = pe_b1[l * H + t];
            for (int k = 0; k < H; ++k) a = fmaf(uL[b][k], w1u[k * H + t], a);
            cbat[(l * NB + b) * H + t] = a;
        }
        const float* w1x = pn_w1 + ((size_t)l * 384 + 256) * H;
        for (int b = 0; b < NB; ++b) {
            float a = pn_b1[l * H + t];
            for (int k = 0; k < H; ++k) a = fmaf(xcL[b][k], w1x[k * H + t], a);
            nbat[(l * NB + b) * H + t] = a;
        }
    }
}

// ---------------------------------------------------------------------------
// k_enc_e_mfma: edge encoder, writes e in SORTED order (gather via permS).
// R10: zero barriers — wave-local staging + wave-local packed stores.
// ---------------------------------------------------------------------------
__global__ __launch_bounds__(256) void k_enc_e_mfma(
    const float* __restrict__ ea,                         // [E,4]
    const int* __restrict__ permS,
    const float* __restrict__ w1, const float* __restrict__ b1,
    const u16* __restrict__ W2et, const float* __restrict__ b2,
    u16* __restrict__ e) {
    __shared__ float SI[TE][H + 4];
    const int t = threadIdx.x;
    const long long e0 = (long long)blockIdx.x * TE;
    const int w = t >> 6, l = t & 63;
    const int m16 = l & 15, g = l >> 4;
    const int row = w * 16 + m16;

    const int src = permS[e0 + row];
    const float4 av = *(const float4*)&ea[(size_t)src * 4];

    bf16x8 afrag[4];
#pragma unroll
    for (int ks = 0; ks < 4; ++ks) {
        const int c0 = ks * 32 + g * 8;
        float hv[8];
        {
            const float4 ba = *(const float4*)&b1[c0];
            const float4 bb = *(const float4*)&b1[c0 + 4];
            hv[0] = ba.x; hv[1] = ba.y; hv[2] = ba.z; hv[3] = ba.w;
            hv[4] = bb.x; hv[5] = bb.y; hv[6] = bb.z; hv[7] = bb.w;
        }
#pragma unroll
        for (int k = 0; k < 4; ++k) {
            const float s = (k == 0) ? av.x : (k == 1) ? av.y : (k == 2) ? av.z : av.w;
            const float4 wa = *(const float4*)&w1[k * H + c0];
            const float4 wb = *(const float4*)&w1[k * H + c0 + 4];
            hv[0] = fmaf(s, wa.x, hv[0]); hv[1] = fmaf(s, wa.y, hv[1]);
            hv[2] = fmaf(s, wa.z, hv[2]); hv[3] = fmaf(s, wa.w, hv[3]);
            hv[4] = fmaf(s, wb.x, hv[4]); hv[5] = fmaf(s, wb.y, hv[5]);
            hv[6] = fmaf(s, wb.z, hv[6]); hv[7] = fmaf(s, wb.w, hv[7]);
        }
#pragma unroll
        for (int j = 0; j < 8; ++j) afrag[ks][j] = (short)f2bf(fmaxf(hv[j], 0.f));
    }

    f32x4 acc[8];
#pragma unroll
    for (int nt = 0; nt < 8; ++nt) {
        const float bb = b2[nt * 16 + m16];
        acc[nt][0] = bb; acc[nt][1] = bb; acc[nt][2] = bb; acc[nt][3] = bb;
    }
#pragma unroll
    for (int ks = 0; ks < 4; ++ks) {
#pragma unroll
        for (int nt = 0; nt < 8; ++nt) {
            const bf16x8 bfr =
                *(const bf16x8*)&W2et[(size_t)(nt * 16 + m16) * H + ks * 32 + g * 8];
            acc[nt] = __builtin_amdgcn_mfma_f32_16x16x32_bf16(afrag[ks], bfr, acc[nt], 0, 0, 0);
        }
    }

#pragma unroll
    for (int nt = 0; nt < 8; ++nt)
#pragma unroll
        for (int j = 0; j < 4; ++j)
            SI[w * 16 + g * 4 + j][nt * 16 + m16] = acc[nt][j];
    // NO barrier: wave-own SI rows; wave-local packed stores.
#pragma unroll
    for (int it = 0; it < 4; ++it) {
        const int u = l + it * 64;            // u < 256
        const int j = u >> 4, c8 = (u & 15) * 8;
        *(uint4*)&e[(size_t)(e0 + w * 16 + j) * H + c8] = pack8(&SI[w * 16 + j][c8]);
    }
}

// ---------------------------------------------------------------------------
// k_enc_n_mfma: node encoder (verified R3).
// ---------------------------------------------------------------------------
__global__ __launch_bounds__(256) void k_enc_n_mfma(
    const float* __restrict__ x,                          // [N,12]
    const float* __restrict__ w1, const float* __restrict__ b1,
    const u16* __restrict__ W2nt, const float* __restrict__ b2,
    float* __restrict__ h) {
    __shared__ float SI[TE][H + 4];
    const int t = threadIdx.x;
    const long long n0 = (long long)blockIdx.x * TE;
    const int w = t >> 6, l = t & 63;
    const int m16 = l & 15, g = l >> 4;
    const int row = w * 16 + m16;
    const long long nr = (n0 + row < NN) ? (n0 + row) : (NN - 1);

    float av[12];
    {
        const float4 a0 = *(const float4*)&x[nr * 12];
        const float4 a1 = *(const float4*)&x[nr * 12 + 4];
        const float4 a2 = *(const float4*)&x[nr * 12 + 8];
        av[0] = a0.x; av[1] = a0.y; av[2] = a0.z; av[3] = a0.w;
        av[4] = a1.x; av[5] = a1.y; av[6] = a1.z; av[7] = a1.w;
        av[8] = a2.x; av[9] = a2.y; av[10] = a2.z; av[11] = a2.w;
    }

    bf16x8 afrag[4];
#pragma unroll
    for (int ks = 0; ks < 4; ++ks) {
        const int c0 = ks * 32 + g * 8;
        float hv[8];
        {
            const float4 ba = *(const float4*)&b1[c0];
            const float4 bb = *(const float4*)&b1[c0 + 4];
            hv[0] = ba.x; hv[1] = ba.y; hv[2] = ba.z; hv[3] = ba.w;
            hv[4] = bb.x; hv[5] = bb.y; hv[6] = bb.z; hv[7] = bb.w;
        }
#pragma unroll
        for (int k = 0; k < 12; ++k) {
            const float s = av[k];
            const float4 wa = *(const float4*)&w1[k * H + c0];
            const float4 wb = *(const float4*)&w1[k * H + c0 + 4];
            hv[0] = fmaf(s, wa.x, hv[0]); hv[1] = fmaf(s, wa.y, hv[1]);
            hv[2] = fmaf(s, wa.z, hv[2]); hv[3] = fmaf(s, wa.w, hv[3]);
            hv[4] = fmaf(s, wb.x, hv[4]); hv[5] = fmaf(s, wb.y, hv[5]);
            hv[6] = fmaf(s, wb.z, hv[6]); hv[7] = fmaf(s, wb.w, hv[7]);
        }
#pragma unroll
        for (int j = 0; j < 8; ++j) afrag[ks][j] = (short)f2bf(fmaxf(hv[j], 0.f));
    }

    f32x4 acc[8];
#pragma unroll
    for (int nt = 0; nt < 8; ++nt) {
        const float bb = b2[nt * 16 + m16];
        acc[nt][0] = bb; acc[nt][1] = bb; acc[nt][2] = bb; acc[nt][3] = bb;
    }
#pragma unroll
    for (int ks = 0; ks < 4; ++ks) {
#pragma unroll
        for (int nt = 0; nt < 8; ++nt) {
            const bf16x8 bfr =
                *(const bf16x8*)&W2nt[(size_t)(nt * 16 + m16) * H + ks * 32 + g * 8];
            acc[nt] = __builtin_amdgcn_mfma_f32_16x16x32_bf16(afrag[ks], bfr, acc[nt], 0, 0, 0);
        }
    }

#pragma unroll
    for (int nt = 0; nt < 8; ++nt)
#pragma unroll
        for (int j = 0; j < 4; ++j)
            SI[w * 16 + g * 4 + j][nt * 16 + m16] = acc[nt][j];
    __syncthreads();
    for (int u = t; u < TE * H / 4; u += 256) {
        const int j = u >> 5, c4 = (u & 31) * 4;
        *(float4*)&h[(size_t)(n0 + j) * H + c4] = *(const float4*)&SI[j][c4];
    }
}

// ---------------------------------------------------------------------------
// k_gemm_dual_mfma (R10): hA = h@Wa + cbat[batch] (folded), hB = h@Wb;
// also zeroes agg[n0..n0+TE) (replaces the separate k_zero pass).
// ---------------------------------------------------------------------------
__global__ __launch_bounds__(256) void k_gemm_dual_mfma(
    const float* __restrict__ h,
    const u16* __restrict__ WaT, const u16* __restrict__ WbT,
    const float* __restrict__ cbatl, const int* __restrict__ batch,
    u16* __restrict__ Ca, u16* __restrict__ Cb, float* __restrict__ agg) {
    __shared__ u16 SI[TE][H + 8];
    __shared__ float CB[NB][H];
    __shared__ int bL[TE];
    const int t = threadIdx.x;
    const long long n0 = (long long)blockIdx.x * TE;
    const int w = t >> 6, l = t & 63;
    const int m16 = l & 15, g = l >> 4;
    const int row = w * 16 + m16;

    // zero this block's agg rows (independent of everything below)
    {
        const float4 z4 = make_float4(0.f, 0.f, 0.f, 0.f);
        for (int u = t; u < TE * H / 4; u += 256) {
            const int j = u >> 5, c4 = (u & 31) * 4;
            *(float4*)&agg[(size_t)(n0 + j) * H + c4] = z4;
        }
    }

    if (t < TE) {
        const long long n = n0 + t;
        bL[t] = batch[n < NN ? n : (NN - 1)];
    }
    for (int i = t; i < NB * H; i += 256) ((float*)CB)[i] = cbatl[i];

    bf16x8 afrag[4];
    {
        const float* hp = h + (size_t)(n0 + row) * H + g * 8;
#pragma unroll
        for (int ks = 0; ks < 4; ++ks) afrag[ks] = ld_f32_bf8(hp + ks * 32);
    }
    __syncthreads();   // bL / CB visible

    f32x4 accA[8], accB[8];
#pragma unroll
    for (int nt = 0; nt < 8; ++nt) {
#pragma unroll
        for (int j = 0; j < 4; ++j)
            accA[nt][j] = CB[bL[w * 16 + g * 4 + j]][nt * 16 + m16];
        accB[nt][0] = 0.f; accB[nt][1] = 0.f; accB[nt][2] = 0.f; accB[nt][3] = 0.f;
    }
#pragma unroll
    for (int ks = 0; ks < 4; ++ks) {
#pragma unroll
        for (int nt = 0; nt < 8; ++nt) {
            const size_t off = (size_t)(nt * 16 + m16) * H + ks * 32 + g * 8;
            const bf16x8 ba = *(const bf16x8*)&WaT[off];
            const bf16x8 bb = *(const bf16x8*)&WbT[off];
            accA[nt] = __builtin_amdgcn_mfma_f32_16x16x32_bf16(afrag[ks], ba, accA[nt], 0, 0, 0);
            accB[nt] = __builtin_amdgcn_mfma_f32_16x16x32_bf16(afrag[ks], bb, accB[nt], 0, 0, 0);
        }
    }

#pragma unroll
    for (int s = 0; s < 2; ++s) {
        __syncthreads();   // protect SI reuse across the two stores
#pragma unroll
        for (int nt = 0; nt < 8; ++nt)
#pragma unroll
            for (int j = 0; j < 4; ++j)
                SI[w * 16 + g * 4 + j][nt * 16 + m16] =
                    f2bf(s ? accB[nt][j] : accA[nt][j]);
        __syncthreads();
        u16* C = s ? Cb : Ca;
        for (int u = t; u < TE * 16; u += 256) {
            const int j = u >> 4, c8 = (u & 15) * 8;
            *(uint4*)&C[(size_t)(n0 + j) * H + c8] = *(const uint4*)&SI[j][c8];
        }
    }
}

// ---------------------------------------------------------------------------
// k_edge_mfma (R10): R9 zero-barrier structure + XCD-chunked blockIdx swizzle
// (bijective since NE/TEE = 5000 is divisible by 8): consecutive sorted-edge
// blocks land on the same XCD -> hA row gathers become per-XCD L2 hits.
// ---------------------------------------------------------------------------
template <bool WRITE_E>
__global__ __launch_bounds__(256, 2) void k_edge_mfma(
    const u16* __restrict__ hA, const u16* __restrict__ hB,
    const u16* __restrict__ W1t, const u16* __restrict__ W2t,
    const float* __restrict__ b2,
    const int* __restrict__ rowS, const int* __restrict__ colS,
    u16* __restrict__ e, float* __restrict__ agg) {
    __shared__ u16 SI[TEE][H + 8];       // bf16; wave w owns rows [w*32,w*32+32)
    const int t = threadIdx.x;
    // XCD-chunked swizzle: gridDim.x % 8 == 0 (5000 = 8*625) -> bijective
    const int bid = (blockIdx.x & 7) * ((int)gridDim.x >> 3) + (blockIdx.x >> 3);
    const long long e0 = (long long)bid * TEE;
    const int w = t >> 6, l = t & 63;
    const int m16 = l & 15, g = l >> 4;

    // e A-fragments for both m-tiles — 8 x 16B, issued up front
    bf16x8 af0[4], af1[4];
    {
        const u16* ep0 = e + (size_t)(e0 + w * 32 + m16) * H + g * 8;
        const u16* ep1 = ep0 + 16 * H;
#pragma unroll
        for (int ks = 0; ks < 4; ++ks) {
            af0[ks] = *(const bf16x8*)(ep0 + ks * 32);
            af1[ks] = *(const bf16x8*)(ep1 + ks * 32);
        }
    }

    // wave-local stage: init = hA'[row] + hB[col] for this wave's 32 edges.
    {
        int rj[8], cj[8];
#pragma unroll
        for (int it = 0; it < 8; ++it) {
            const int j = (l + it * 64) >> 4;
            rj[it] = rowS[e0 + w * 32 + j];
            cj[it] = colS[e0 + w * 32 + j];
        }
#pragma unroll
        for (int it = 0; it < 8; ++it) {
            const int u = l + it * 64;
            const int j = u >> 4, c8 = (u & 15) * 8;
            float va[8], vb[8], sm[8];
            unpack8(*(const uint4*)&hA[(size_t)rj[it] * H + c8], va);
            unpack8(*(const uint4*)&hB[(size_t)cj[it] * H + c8], vb);
#pragma unroll
            for (int q = 0; q < 8; ++q) sm[q] = va[q] + vb[q];
            *(uint4*)&SI[w * 32 + j][c8] = pack8(sm);
        }
    }
    // NO barrier: same-wave ds_write -> ds_read ordering suffices.

    // ---- GEMM1: acc = init + e @ W1c (B-frag shared across both m-tiles) ----
    f32x4 acc0[8], acc1[8];
#pragma unroll
    for (int nt = 0; nt < 8; ++nt) {
#pragma unroll
        for (int j = 0; j < 4; ++j) {
            acc0[nt][j] = bf2f(SI[w * 32 + g * 4 + j][nt * 16 + m16]);
            acc1[nt][j] = bf2f(SI[w * 32 + 16 + g * 4 + j][nt * 16 + m16]);
        }
    }
#pragma unroll
    for (int ks = 0; ks < 4; ++ks) {
#pragma unroll
        for (int nt = 0; nt < 8; ++nt) {
            const bf16x8 bfr =
                *(const bf16x8*)&W1t[(size_t)(nt * 16 + m16) * H + ks * 32 + g * 8];
            acc0[nt] = __builtin_amdgcn_mfma_f32_16x16x32_bf16(af0[ks], bfr, acc0[nt], 0, 0, 0);
            acc1[nt] = __builtin_amdgcn_mfma_f32_16x16x32_bf16(af1[ks], bfr, acc1[nt], 0, 0, 0);
        }
    }

    // hidden = relu -> SI (wave-own rows; same-wave DS ordering, no barrier)
#pragma unroll
    for (int nt = 0; nt < 8; ++nt)
#pragma unroll
        for (int j = 0; j < 4; ++j) {
            SI[w * 32 + g * 4 + j][nt * 16 + m16]      = f2bf(fmaxf(acc0[nt][j], 0.f));
            SI[w * 32 + 16 + g * 4 + j][nt * 16 + m16] = f2bf(fmaxf(acc1[nt][j], 0.f));
        }

    // ---- GEMM2: REUSE acc0/acc1 (re-init with b2) ----
#pragma unroll
    for (int nt = 0; nt < 8; ++nt) {
        const float bb = b2[nt * 16 + m16];
        acc0[nt][0] = bb; acc0[nt][1] = bb; acc0[nt][2] = bb; acc0[nt][3] = bb;
        acc1[nt][0] = bb; acc1[nt][1] = bb; acc1[nt][2] = bb; acc1[nt][3] = bb;
    }
#pragma unroll
    for (int ks = 0; ks < 4; ++ks) {
        const bf16x8 a20 = *(const bf16x8*)&SI[w * 32 + m16][ks * 32 + g * 8];
        const bf16x8 a21 = *(const bf16x8*)&SI[w * 32 + 16 + m16][ks * 32 + g * 8];
#pragma unroll
        for (int nt = 0; nt < 8; ++nt) {
            const bf16x8 bfr =
                *(const bf16x8*)&W2t[(size_t)(nt * 16 + m16) * H + ks * 32 + g * 8];
            acc0[nt] = __builtin_amdgcn_mfma_f32_16x16x32_bf16(a20, bfr, acc0[nt], 0, 0, 0);
            acc1[nt] = __builtin_amdgcn_mfma_f32_16x16x32_bf16(a21, bfr, acc1[nt], 0, 0, 0);
        }
    }

    // agg: f32 register atomics, one merge chain over the 8 sorted rows/lane
    {
        int r[8];
#pragma unroll
        for (int j = 0; j < 4; ++j) {
            r[j]     = rowS[e0 + w * 32 + g * 4 + j];
            r[4 + j] = rowS[e0 + w * 32 + 16 + g * 4 + j];
        }
#pragma unroll
        for (int nt = 0; nt < 8; ++nt) {
            const int c = nt * 16 + m16;
            float v[8];
#pragma unroll
            for (int j = 0; j < 4; ++j) { v[j] = acc0[nt][j]; v[4 + j] = acc1[nt][j]; }
            float s = v[0];
            int prev = r[0];
#pragma unroll
            for (int j = 1; j < 8; ++j) {
                if (r[j] == prev) s += v[j];
                else { atomicAdd(&agg[(size_t)prev * H + c], s); s = v[j]; prev = r[j]; }
            }
            atomicAdd(&agg[(size_t)prev * H + c], s);
        }
    }

    if (WRITE_E) {
        // stage output to wave-own SI rows, then wave-local packed stores
#pragma unroll
        for (int nt = 0; nt < 8; ++nt)
#pragma unroll
            for (int j = 0; j < 4; ++j) {
                SI[w * 32 + g * 4 + j][nt * 16 + m16]      = f2bf(acc0[nt][j]);
                SI[w * 32 + 16 + g * 4 + j][nt * 16 + m16] = f2bf(acc1[nt][j]);
            }
        // NO barrier: wave writes its own 32 edges
#pragma unroll
        for (int it = 0; it < 8; ++it) {
            const int u = l + it * 64;
            const int j = u >> 4, c8 = (u & 15) * 8;
            *(uint4*)&e[(size_t)(e0 + w * 32 + j) * H + c8] = *(const uint4*)&SI[w * 32 + j][c8];
        }
    }
}

// ---------------------------------------------------------------------------
// k_node_mfma (R10): zero barriers — wave-own SI rows, direct global
// nbat/batch reads, accumulator reuse across the two GEMM stages.
// h += relu(h@Wn1a + agg@Wn1b + nbat[batch]) @ Wn2 + bn2
// ---------------------------------------------------------------------------
__global__ __launch_bounds__(256) void k_node_mfma(
    const u16* __restrict__ Wn1aT, const u16* __restrict__ Wn1bT,
    const u16* __restrict__ Wn2T, const float* __restrict__ bn2,
    const float* __restrict__ nbatl, const int* __restrict__ batch,
    const float* __restrict__ agg, float* __restrict__ h) {
    __shared__ float SI[TE][H + 4];
    const int t = threadIdx.x;
    const long long n0 = (long long)blockIdx.x * TE;
    const int w = t >> 6, l = t & 63;
    const int m16 = l & 15, g = l >> 4;
    const int row = w * 16 + m16;

    bf16x8 afrag[4];
    {
        const float* hp = h + (size_t)(n0 + row) * H + g * 8;
#pragma unroll
        for (int ks = 0; ks < 4; ++ks) afrag[ks] = ld_f32_bf8(hp + ks * 32);
    }

    // batch for this lane's 4 fragment rows (direct global, L1-hot)
    int bj[4];
#pragma unroll
    for (int j = 0; j < 4; ++j) {
        const long long n = n0 + w * 16 + g * 4 + j;
        bj[j] = batch[n < NN ? n : (NN - 1)];
    }

    f32x4 acc[8];
#pragma unroll
    for (int nt = 0; nt < 8; ++nt)
#pragma unroll
        for (int j = 0; j < 4; ++j)
            acc[nt][j] = nbatl[(size_t)bj[j] * H + nt * 16 + m16];

#pragma unroll
    for (int ks = 0; ks < 4; ++ks)
#pragma unroll
        for (int nt = 0; nt < 8; ++nt) {
            const bf16x8 bfr =
                *(const bf16x8*)&Wn1aT[(size_t)(nt * 16 + m16) * H + ks * 32 + g * 8];
            acc[nt] = __builtin_amdgcn_mfma_f32_16x16x32_bf16(afrag[ks], bfr, acc[nt], 0, 0, 0);
        }

    {
        const float* ap = agg + (size_t)(n0 + row) * H + g * 8;
#pragma unroll
        for (int ks = 0; ks < 4; ++ks) afrag[ks] = ld_f32_bf8(ap + ks * 32);
    }
#pragma unroll
    for (int ks = 0; ks < 4; ++ks)
#pragma unroll
        for (int nt = 0; nt < 8; ++nt) {
            const bf16x8 bfr =
                *(const bf16x8*)&Wn1bT[(size_t)(nt * 16 + m16) * H + ks * 32 + g * 8];
            acc[nt] = __builtin_amdgcn_mfma_f32_16x16x32_bf16(afrag[ks], bfr, acc[nt], 0, 0, 0);
        }

    // hidden = relu(acc) -> wave-own SI rows (no barrier)
#pragma unroll
    for (int nt = 0; nt < 8; ++nt)
#pragma unroll
        for (int j = 0; j < 4; ++j)
            SI[w * 16 + g * 4 + j][nt * 16 + m16] = fmaxf(acc[nt][j], 0.f);

    // GEMM2: reuse acc (re-init with bn2); A-frags from wave-own SI rows
#pragma unroll
    for (int nt = 0; nt < 8; ++nt) {
        const float bb = bn2[nt * 16 + m16];
        acc[nt][0] = bb; acc[nt][1] = bb; acc[nt][2] = bb; acc[nt][3] = bb;
    }
#pragma unroll
    for (int ks = 0; ks < 4; ++ks) {
        bf16x8 a2;
        const float* hp = &SI[w * 16 + m16][ks * 32 + g * 8];
#pragma unroll
        for (int j = 0; j < 8; ++j) a2[j] = (short)f2bf(hp[j]);
#pragma unroll
        for (int nt = 0; nt < 8; ++nt) {
            const bf16x8 bfr =
                *(const bf16x8*)&Wn2T[(size_t)(nt * 16 + m16) * H + ks * 32 + g * 8];
            acc[nt] = __builtin_amdgcn_mfma_f32_16x16x32_bf16(a2, bfr, acc[nt], 0, 0, 0);
        }
    }

    // stage output to wave-own SI rows (writes depend on MFMAs which depend
    // on the a2 reads — same-wave DS order safe), then wave-local h += RMW
#pragma unroll
    for (int nt = 0; nt < 8; ++nt)
#pragma unroll
        for (int j = 0; j < 4; ++j)
            SI[w * 16 + g * 4 + j][nt * 16 + m16] = acc[nt][j];

#pragma unroll
    for (int it = 0; it < 8; ++it) {
        const int u = l + it * 64;            // u < 512
        const int j = u >> 5, c4 = (u & 31) * 4;
        float4 hv = *(const float4*)&h[(size_t)(n0 + w * 16 + j) * H + c4];
        const float4 sv = *(const float4*)&SI[w * 16 + j][c4];
        hv.x += sv.x; hv.y += sv.y; hv.z += sv.z; hv.w += sv.w;
        *(float4*)&h[(size_t)(n0 + w * 16 + j) * H + c4] = hv;
    }
}

// ---------------------------------------------------------------------------
// k_dec_mfma: decoder.  Layer 1 (H x H) via MFMA; 3-col layer 2 via VALU.
// ---------------------------------------------------------------------------
__global__ __launch_bounds__(256) void k_dec_mfma(
    const float* __restrict__ h,
    const u16* __restrict__ W1dt, const float* __restrict__ b1,
    const float* __restrict__ w2, const float* __restrict__ b2,
    float* __restrict__ out) {
    __shared__ float SI[TE][H + 4];
    const int t = threadIdx.x;
    const long long n0 = (long long)blockIdx.x * TE;
    const int w = t >> 6, l = t & 63;
    const int m16 = l & 15, g = l >> 4;
    const int row = w * 16 + m16;

    bf16x8 afrag[4];
    {
        const float* hp = h + (size_t)(n0 + row) * H + g * 8;
#pragma unroll
        for (int ks = 0; ks < 4; ++ks) afrag[ks] = ld_f32_bf8(hp + ks * 32);
    }

    f32x4 acc[8];
#pragma unroll
    for (int nt = 0; nt < 8; ++nt) {
        const float bb = b1[nt * 16 + m16];
        acc[nt][0] = bb; acc[nt][1] = bb; acc[nt][2] = bb; acc[nt][3] = bb;
    }
#pragma unroll
    for (int ks = 0; ks < 4; ++ks) {
#pragma unroll
        for (int nt = 0; nt < 8; ++nt) {
            const bf16x8 bfr =
                *(const bf16x8*)&W1dt[(size_t)(nt * 16 + m16) * H + ks * 32 + g * 8];
            acc[nt] = __builtin_amdgcn_mfma_f32_16x16x32_bf16(afrag[ks], bfr, acc[nt], 0, 0, 0);
        }
    }

    // hidden = relu -> SI
#pragma unroll
    for (int nt = 0; nt < 8; ++nt)
#pragma unroll
        for (int j = 0; j < 4; ++j)
            SI[w * 16 + g * 4 + j][nt * 16 + m16] = fmaxf(acc[nt][j], 0.f);
    __syncthreads();

    if (t < TE * 3) {
        const int n = t / 3, c = t - n * 3;
        if (n0 + n < NN) {
            float v = b2[c];
            for (int k = 0; k < H; ++k) v = fmaf(SI[n][k], w2[k * 3 + c], v);
            out[(size_t)(n0 + n) * 3 + c] = v;
        }
    }
}

// ---------------------------------------------------------------------------
extern "C" void kernel_launch(void* const* d_in, const int* in_sizes, int n_in,
                              void* d_out, int out_size, void* d_ws, size_t ws_size,
                              hipStream_t stream) {
    const float* x          = (const float*)d_in[0];
    const int*   edge_index = (const int*)d_in[1];
    const float* edge_attr  = (const float*)d_in[2];
    const float* cond       = (const float*)d_in[3];
    const int*   batch      = (const int*)d_in[4];
    const float* enc_node_w1 = (const float*)d_in[5];
    const float* enc_node_b1 = (const float*)d_in[6];
    const float* enc_node_w2 = (const float*)d_in[7];
    const float* enc_node_b2 = (const float*)d_in[8];
    const float* enc_edge_w1 = (const float*)d_in[9];
    const float* enc_edge_b1 = (const float*)d_in[10];
    const float* enc_edge_w2 = (const float*)d_in[11];
    const float* enc_edge_b2 = (const float*)d_in[12];
    const float* enc_cond_w1 = (const float*)d_in[13];
    const float* enc_cond_b1 = (const float*)d_in[14];
    const float* enc_cond_w2 = (const float*)d_in[15];
    const float* enc_cond_b2 = (const float*)d_in[16];
    const float* attn_wv = (const float*)d_in[17];
    const float* attn_bv = (const float*)d_in[18];
    const float* attn_wo = (const float*)d_in[19];
    const float* attn_bo = (const float*)d_in[20];
    const float* pe_w1 = (const float*)d_in[21];
    const float* pe_b1 = (const float*)d_in[22];
    const float* pe_w2 = (const float*)d_in[23];
    const float* pe_b2 = (const float*)d_in[24];
    const float* pn_w1 = (const float*)d_in[25];
    const float* pn_b1 = (const float*)d_in[26];
    const float* pn_w2 = (const float*)d_in[27];
    const float* pn_b2 = (const float*)d_in[28];
    const float* dec_w1 = (const float*)d_in[29];
    const float* dec_b1 = (const float*)d_in[30];
    const float* dec_w2 = (const float*)d_in[31];
    const float* dec_b2 = (const float*)d_in[32];

    // workspace (~250 MB): node arrays padded to NNP rows
    u16*   e    = (u16*)d_ws;                                  // NE*H bf16
    float* h    = (float*)((char*)d_ws + (size_t)NE * H * 2);  // NNP*H f32
    float* agg  = h + (size_t)NNP * H;                         // NNP*H f32
    u16*   hA   = (u16*)(agg + (size_t)NNP * H);               // NNP*H bf16
    u16*   hB   = hA + (size_t)NNP * H;                        // NNP*H bf16
    float* cbat = (float*)(hB + (size_t)NNP * H);              // NL*NB*H f32
    float* nbat = cbat + NL * NB * H;                          // NL*NB*H f32
    u16*   W1t   = (u16*)(nbat + NL * NB * H);                 // NL*H*H bf16 each:
    u16*   W2t   = W1t  + (size_t)NL * H * H;
    u16*   WaT   = W2t  + (size_t)NL * H * H;
    u16*   WbT   = WaT  + (size_t)NL * H * H;
    u16*   Wn1aT = WbT  + (size_t)NL * H * H;
    u16*   Wn1bT = Wn1aT + (size_t)NL * H * H;
    u16*   Wn2T  = Wn1bT + (size_t)NL * H * H;
    u16*   W2et  = Wn2T + (size_t)NL * H * H;                  // H*H bf16
    u16*   W2nt  = W2et + (size_t)H * H;                       // H*H bf16
    u16*   W1dt  = W2nt + (size_t)H * H;                       // H*H bf16
    u32*   cnt   = (u32*)(W1dt + (size_t)H * H);               // NNP u32
    int*   permS = (int*)(cnt + NNP);                          // NE int
    int*   rowS  = permS + NE;                                 // NE int (sorted rows)
    int*   colS  = rowS + NE;                                  // NE int (sorted cols)

    const int* rowi = edge_index;
    const int* coli = edge_index + NE;
    float* out = (float*)d_out;

    // ---- counting sort of edges by row (once per launch) ----
    k_zero<<<(NNP / 4 + 255) / 256, 256, 0, stream>>>((float*)cnt, NNP / 4);
    k_hist<<<NE / 256, 256, 0, stream>>>(rowi, cnt);
    k_scan<<<1, 1024, 0, stream>>>(cnt);
    k_scatter<<<NE / 256, 256, 0, stream>>>(rowi, coli, cnt, permS, rowS, colS);

    k_prep<<<dim3(NL, 8), 256, 0, stream>>>(pe_w1, pe_w2, pn_w1, pn_w2,
                                            enc_edge_w2, enc_node_w2, dec_w1,
                                            W1t, W2t, WaT, WbT,
                                            Wn1aT, Wn1bT, Wn2T, W2et, W2nt, W1dt);
    k_small<<<1, 128, 0, stream>>>(cond, enc_cond_w1, enc_cond_b1, enc_cond_w2, enc_cond_b2,
                                   attn_wv, attn_bv, attn_wo, attn_bo,
                                   pe_w1, pe_b1, pn_w1, pn_b1, cbat, nbat);
    k_enc_n_mfma<<<NNP / TE, 256, 0, stream>>>(
        x, enc_node_w1, enc_node_b1, W2nt, enc_node_b2, h);
    k_enc_e_mfma<<<NE / TE, 256, 0, stream>>>(
        edge_attr, permS, enc_edge_w1, enc_edge_b1, W2et, enc_edge_b2, e);

    for (int l = 0; l < NL; ++l) {
        k_gemm_dual_mfma<<<NNP / TE, 256, 0, stream>>>(
            h, WaT + (size_t)l * H * H, WbT + (size_t)l * H * H,
            cbat + l * NB * H, batch, hA, hB, agg);
        if (l < NL - 1)
            k_edge_mfma<true><<<NE / TEE, 256, 0, stream>>>(
                hA, hB, W1t + (size_t)l * H * H, W2t + (size_t)l * H * H,
                pe_b2 + l * H, rowS, colS, e, agg);
        else
            k_edge_mfma<false><<<NE / TEE, 256, 0, stream>>>(
                hA, hB, W1t + (size_t)l * H * H, W2t + (size_t)l * H * H,
                pe_b2 + l * H, rowS, colS, e, agg);
        k_node_mfma<<<NNP / TE, 256, 0, stream>>>(
            Wn1aT + (size_t)l * H * H, Wn1bT + (size_t)l * H * H,
            Wn2T + (size_t)l * H * H, pn_b2 + l * H,
            nbat + l * NB * H, batch, agg, h);
    }
    k_dec_mfma<<<NNP / TE, 256, 0, stream>>>(h, W1dt, dec_b1, dec_w2, dec_b2, out);
}

// Round 11
// 2304.330 us; speedup vs baseline: 1.0255x; 1.0064x over previous
//
#include <hip/hip_runtime.h>
#include <cstddef>

#define NN 50000
#define NNP 50048   // NN padded to multiple of TE (node arrays in workspace)
#define NE 640000
#define NB 4
#define H  128
#define NL 4
#define TE 64    // rows per block for node/enc MFMA kernels
#define TEE 128  // edges per block for k_edge_mfma (32 edges/wave x 4 waves)

typedef unsigned int u32;
typedef unsigned short u16;   // raw bf16 (intermediates only; I/O is fp32)
typedef __attribute__((ext_vector_type(8))) short bf16x8;
typedef __attribute__((ext_vector_type(4))) float f32x4;

__device__ __forceinline__ float bf2f(u16 s) {
    union { u32 u; float f; } v; v.u = ((u32)s) << 16; return v.f;
}
__device__ __forceinline__ u16 f2bf(float f) {
    union { float f; u32 u; } v; v.f = f;
    u32 u = v.u;
    u += 0x7FFF + ((u >> 16) & 1);   // RNE
    return (u16)(u >> 16);
}
__device__ __forceinline__ void unpack8(uint4 raw, float* d) {
    d[0] = bf2f(raw.x & 0xFFFF); d[1] = bf2f(raw.x >> 16);
    d[2] = bf2f(raw.y & 0xFFFF); d[3] = bf2f(raw.y >> 16);
    d[4] = bf2f(raw.z & 0xFFFF); d[5] = bf2f(raw.z >> 16);
    d[6] = bf2f(raw.w & 0xFFFF); d[7] = bf2f(raw.w >> 16);
}
__device__ __forceinline__ uint4 pack8(const float* s) {
    uint4 pk;
    pk.x = (u32)f2bf(s[0]) | ((u32)f2bf(s[1]) << 16);
    pk.y = (u32)f2bf(s[2]) | ((u32)f2bf(s[3]) << 16);
    pk.z = (u32)f2bf(s[4]) | ((u32)f2bf(s[5]) << 16);
    pk.w = (u32)f2bf(s[6]) | ((u32)f2bf(s[7]) << 16);
    return pk;
}
// fp32 row-slice (8 floats, 16B-aligned) -> bf16x8 A-fragment
__device__ __forceinline__ bf16x8 ld_f32_bf8(const float* __restrict__ p) {
    const float4 a = *(const float4*)p;
    const float4 b = *(const float4*)(p + 4);
    bf16x8 r;
    r[0] = (short)f2bf(a.x); r[1] = (short)f2bf(a.y);
    r[2] = (short)f2bf(a.z); r[3] = (short)f2bf(a.w);
    r[4] = (short)f2bf(b.x); r[5] = (short)f2bf(b.y);
    r[6] = (short)f2bf(b.z); r[7] = (short)f2bf(b.w);
    return r;
}

// ---------------------------------------------------------------------------
__global__ __launch_bounds__(256) void k_zero(float* __restrict__ p, int n4) {
    const int i = blockIdx.x * 256 + threadIdx.x;
    if (i < n4) ((float4*)p)[i] = make_float4(0.f, 0.f, 0.f, 0.f);
}

// ---------------------------------------------------------------------------
// Counting sort of edges by destination row.
// ---------------------------------------------------------------------------
__global__ __launch_bounds__(256) void k_hist(const int* __restrict__ rowi,
                                              u32* __restrict__ cnt) {
    const int i = blockIdx.x * 256 + threadIdx.x;
    if (i < NE) atomicAdd(&cnt[rowi[i]], 1u);
}

__global__ __launch_bounds__(1024) void k_scan(u32* __restrict__ cnt) {
    __shared__ u32 part[1024];
    const int t = threadIdx.x;
    const int CHUNK = (NN + 1023) / 1024;
    const int lo = t * CHUNK;
    const int hi = (lo + CHUNK < NN) ? lo + CHUNK : NN;
    u32 s = 0;
    for (int i = lo; i < hi; ++i) s += cnt[i];
    part[t] = s;
    __syncthreads();
    for (int ofs = 1; ofs < 1024; ofs <<= 1) {
        const u32 v = (t >= ofs) ? part[t - ofs] : 0u;
        __syncthreads();
        part[t] += v;
        __syncthreads();
    }
    u32 run = (t == 0) ? 0u : part[t - 1];   // exclusive prefix
    for (int i = lo; i < hi; ++i) { const u32 c = cnt[i]; cnt[i] = run; run += c; }
}

__global__ __launch_bounds__(256) void k_scatter(const int* __restrict__ rowi,
                                                 const int* __restrict__ coli,
                                                 u32* __restrict__ off,
                                                 int* __restrict__ permS,
                                                 int* __restrict__ rowS,
                                                 int* __restrict__ colS) {
    const int i = blockIdx.x * 256 + threadIdx.x;
    if (i < NE) {
        const int r = rowi[i];
        const u32 p = atomicAdd(&off[r], 1u);
        permS[p] = i; rowS[p] = r; colS[p] = coli[i];
    }
}

// ---------------------------------------------------------------------------
// k_prep: weights -> bf16, transposed to [n][k] for contiguous MFMA B-frags.
// ---------------------------------------------------------------------------
__global__ __launch_bounds__(256) void k_prep(
    const float* __restrict__ pe_w1, const float* __restrict__ pe_w2,
    const float* __restrict__ pn_w1, const float* __restrict__ pn_w2,
    const float* __restrict__ ew2,   const float* __restrict__ nw2,
    const float* __restrict__ dw1,
    u16* __restrict__ W1t, u16* __restrict__ W2t,
    u16* __restrict__ WaT, u16* __restrict__ WbT,
    u16* __restrict__ Wn1aT, u16* __restrict__ Wn1bT, u16* __restrict__ Wn2T,
    u16* __restrict__ W2et, u16* __restrict__ W2nt, u16* __restrict__ W1dt) {
    const int li = blockIdx.x;
    const float* src; u16* dst;
    switch (blockIdx.y) {
        case 0: src = pe_w1 + ((size_t)li * 512 + 256) * H; dst = W1t  + (size_t)li * H * H; break;
        case 1: src = pe_w2 + (size_t)li * H * H;           dst = W2t  + (size_t)li * H * H; break;
        case 2: src = pe_w1 + (size_t)li * 512 * H;         dst = WaT  + (size_t)li * H * H; break;
        case 3: src = pe_w1 + ((size_t)li * 512 + 128) * H; dst = WbT  + (size_t)li * H * H; break;
        case 4: src = pn_w1 + (size_t)li * 384 * H;         dst = Wn1aT + (size_t)li * H * H; break;
        case 5: src = pn_w1 + ((size_t)li * 384 + 128) * H; dst = Wn1bT + (size_t)li * H * H; break;
        case 6: src = pn_w2 + (size_t)li * H * H;           dst = Wn2T + (size_t)li * H * H; break;
        default:
            if (li == 0)      { src = ew2; dst = W2et; }
            else if (li == 1) { src = nw2; dst = W2nt; }
            else if (li == 2) { src = dw1; dst = W1dt; }
            else return;
            break;
    }
    for (int idx = threadIdx.x; idx < H * H; idx += 256) {
        const int n = idx >> 7, k = idx & 127;
        dst[idx] = f2bf(src[(size_t)k * H + n]);
    }
}

// ---------------------------------------------------------------------------
// k_small (verified R13): u, x_cond, per-layer consts cbat/nbat.
// ---------------------------------------------------------------------------
__global__ __launch_bounds__(128) void k_small(
    const float* __restrict__ cond,
    const float* __restrict__ ecw1, const float* __restrict__ ecb1,
    const float* __restrict__ ecw2, const float* __restrict__ ecb2,
    const float* __restrict__ wv, const float* __restrict__ bv,
    const float* __restrict__ wo, const float* __restrict__ bo,
    const float* __restrict__ pe_w1, const float* __restrict__ pe_b1,
    const float* __restrict__ pn_w1, const float* __restrict__ pn_b1,
    float* __restrict__ cbat, float* __restrict__ nbat) {
    __shared__ float tmp[NB][H];
    __shared__ float uL[NB][H];
    __shared__ float xcL[NB][H];
    const int t = threadIdx.x;
    for (int b = 0; b < NB; ++b) {
        float a = ecb1[t];
        for (int k = 0; k < 10; ++k) a = fmaf(cond[b * 10 + k], ecw1[k * H + t], a);
        tmp[b][t] = fmaxf(a, 0.f);
    }
    __syncthreads();
    for (int b = 0; b < NB; ++b) {
        float a = ecb2[t];
        for (int k = 0; k < H; ++k) a = fmaf(tmp[b][k], ecw2[k * H + t], a);
        uL[b][t] = a;
    }
    __syncthreads();
    for (int b = 0; b < NB; ++b) {
        float a = bv[t];
        for (int k = 0; k < H; ++k) a = fmaf(uL[b][k], wv[k * H + t], a);
        tmp[b][t] = a;
    }
    __syncthreads();
    for (int b = 0; b < NB; ++b) {
        float a = bo[t];
        for (int k = 0; k < H; ++k) a = fmaf(tmp[b][k], wo[k * H + t], a);
        xcL[b][t] = a;
    }
    __syncthreads();
    for (int l = 0; l < NL; ++l) {
        const float* w1u = pe_w1 + ((size_t)l * 512 + 384) * H;
        for (int b = 0; b < NB; ++b) {
            float a = pe_b1[l * H + t];
            for (int k = 0; k < H; ++k) a = fmaf(uL[b][k], w1u[k * H + t], a);
            cbat[(l * NB + b) * H + t] = a;
        }
        const float* w1x = pn_w1 + ((size_t)l * 384 + 256) * H;
        for (int b = 0; b < NB; ++b) {
            float a = pn_b1[l * H + t];
            for (int k = 0; k < H; ++k) a = fmaf(xcL[b][k], w1x[k * H + t], a);
            nbat[(l * NB + b) * H + t] = a;
        }
    }
}

// ---------------------------------------------------------------------------
// k_enc_e_mfma: edge encoder, writes e in SORTED order (gather via permS).
// Zero barriers — wave-local staging + wave-local packed stores (verified R10).
// ---------------------------------------------------------------------------
__global__ __launch_bounds__(256) void k_enc_e_mfma(
    const float* __restrict__ ea,                         // [E,4]
    const int* __restrict__ permS,
    const float* __restrict__ w1, const float* __restrict__ b1,
    const u16* __restrict__ W2et, const float* __restrict__ b2,
    u16* __restrict__ e) {
    __shared__ float SI[TE][H + 4];
    const int t = threadIdx.x;
    const long long e0 = (long long)blockIdx.x * TE;
    const int w = t >> 6, l = t & 63;
    const int m16 = l & 15, g = l >> 4;
    const int row = w * 16 + m16;

    const int src = permS[e0 + row];
    const float4 av = *(const float4*)&ea[(size_t)src * 4];

    bf16x8 afrag[4];
#pragma unroll
    for (int ks = 0; ks < 4; ++ks) {
        const int c0 = ks * 32 + g * 8;
        float hv[8];
        {
            const float4 ba = *(const float4*)&b1[c0];
            const float4 bb = *(const float4*)&b1[c0 + 4];
            hv[0] = ba.x; hv[1] = ba.y; hv[2] = ba.z; hv[3] = ba.w;
            hv[4] = bb.x; hv[5] = bb.y; hv[6] = bb.z; hv[7] = bb.w;
        }
#pragma unroll
        for (int k = 0; k < 4; ++k) {
            const float s = (k == 0) ? av.x : (k == 1) ? av.y : (k == 2) ? av.z : av.w;
            const float4 wa = *(const float4*)&w1[k * H + c0];
            const float4 wb = *(const float4*)&w1[k * H + c0 + 4];
            hv[0] = fmaf(s, wa.x, hv[0]); hv[1] = fmaf(s, wa.y, hv[1]);
            hv[2] = fmaf(s, wa.z, hv[2]); hv[3] = fmaf(s, wa.w, hv[3]);
            hv[4] = fmaf(s, wb.x, hv[4]); hv[5] = fmaf(s, wb.y, hv[5]);
            hv[6] = fmaf(s, wb.z, hv[6]); hv[7] = fmaf(s, wb.w, hv[7]);
        }
#pragma unroll
        for (int j = 0; j < 8; ++j) afrag[ks][j] = (short)f2bf(fmaxf(hv[j], 0.f));
    }

    f32x4 acc[8];
#pragma unroll
    for (int nt = 0; nt < 8; ++nt) {
        const float bb = b2[nt * 16 + m16];
        acc[nt][0] = bb; acc[nt][1] = bb; acc[nt][2] = bb; acc[nt][3] = bb;
    }
#pragma unroll
    for (int ks = 0; ks < 4; ++ks) {
#pragma unroll
        for (int nt = 0; nt < 8; ++nt) {
            const bf16x8 bfr =
                *(const bf16x8*)&W2et[(size_t)(nt * 16 + m16) * H + ks * 32 + g * 8];
            acc[nt] = __builtin_amdgcn_mfma_f32_16x16x32_bf16(afrag[ks], bfr, acc[nt], 0, 0, 0);
        }
    }

#pragma unroll
    for (int nt = 0; nt < 8; ++nt)
#pragma unroll
        for (int j = 0; j < 4; ++j)
            SI[w * 16 + g * 4 + j][nt * 16 + m16] = acc[nt][j];
    // NO barrier: wave-own SI rows; wave-local packed stores.
#pragma unroll
    for (int it = 0; it < 4; ++it) {
        const int u = l + it * 64;            // u < 256
        const int j = u >> 4, c8 = (u & 15) * 8;
        *(uint4*)&e[(size_t)(e0 + w * 16 + j) * H + c8] = pack8(&SI[w * 16 + j][c8]);
    }
}

// ---------------------------------------------------------------------------
// k_enc_n_mfma: node encoder (verified R3).
// ---------------------------------------------------------------------------
__global__ __launch_bounds__(256) void k_enc_n_mfma(
    const float* __restrict__ x,                          // [N,12]
    const float* __restrict__ w1, const float* __restrict__ b1,
    const u16* __restrict__ W2nt, const float* __restrict__ b2,
    float* __restrict__ h) {
    __shared__ float SI[TE][H + 4];
    const int t = threadIdx.x;
    const long long n0 = (long long)blockIdx.x * TE;
    const int w = t >> 6, l = t & 63;
    const int m16 = l & 15, g = l >> 4;
    const int row = w * 16 + m16;
    const long long nr = (n0 + row < NN) ? (n0 + row) : (NN - 1);

    float av[12];
    {
        const float4 a0 = *(const float4*)&x[nr * 12];
        const float4 a1 = *(const float4*)&x[nr * 12 + 4];
        const float4 a2 = *(const float4*)&x[nr * 12 + 8];
        av[0] = a0.x; av[1] = a0.y; av[2] = a0.z; av[3] = a0.w;
        av[4] = a1.x; av[5] = a1.y; av[6] = a1.z; av[7] = a1.w;
        av[8] = a2.x; av[9] = a2.y; av[10] = a2.z; av[11] = a2.w;
    }

    bf16x8 afrag[4];
#pragma unroll
    for (int ks = 0; ks < 4; ++ks) {
        const int c0 = ks * 32 + g * 8;
        float hv[8];
        {
            const float4 ba = *(const float4*)&b1[c0];
            const float4 bb = *(const float4*)&b1[c0 + 4];
            hv[0] = ba.x; hv[1] = ba.y; hv[2] = ba.z; hv[3] = ba.w;
            hv[4] = bb.x; hv[5] = bb.y; hv[6] = bb.z; hv[7] = bb.w;
        }
#pragma unroll
        for (int k = 0; k < 12; ++k) {
            const float s = av[k];
            const float4 wa = *(const float4*)&w1[k * H + c0];
            const float4 wb = *(const float4*)&w1[k * H + c0 + 4];
            hv[0] = fmaf(s, wa.x, hv[0]); hv[1] = fmaf(s, wa.y, hv[1]);
            hv[2] = fmaf(s, wa.z, hv[2]); hv[3] = fmaf(s, wa.w, hv[3]);
            hv[4] = fmaf(s, wb.x, hv[4]); hv[5] = fmaf(s, wb.y, hv[5]);
            hv[6] = fmaf(s, wb.z, hv[6]); hv[7] = fmaf(s, wb.w, hv[7]);
        }
#pragma unroll
        for (int j = 0; j < 8; ++j) afrag[ks][j] = (short)f2bf(fmaxf(hv[j], 0.f));
    }

    f32x4 acc[8];
#pragma unroll
    for (int nt = 0; nt < 8; ++nt) {
        const float bb = b2[nt * 16 + m16];
        acc[nt][0] = bb; acc[nt][1] = bb; acc[nt][2] = bb; acc[nt][3] = bb;
    }
#pragma unroll
    for (int ks = 0; ks < 4; ++ks) {
#pragma unroll
        for (int nt = 0; nt < 8; ++nt) {
            const bf16x8 bfr =
                *(const bf16x8*)&W2nt[(size_t)(nt * 16 + m16) * H + ks * 32 + g * 8];
            acc[nt] = __builtin_amdgcn_mfma_f32_16x16x32_bf16(afrag[ks], bfr, acc[nt], 0, 0, 0);
        }
    }

#pragma unroll
    for (int nt = 0; nt < 8; ++nt)
#pragma unroll
        for (int j = 0; j < 4; ++j)
            SI[w * 16 + g * 4 + j][nt * 16 + m16] = acc[nt][j];
    __syncthreads();
    for (int u = t; u < TE * H / 4; u += 256) {
        const int j = u >> 5, c4 = (u & 31) * 4;
        *(float4*)&h[(size_t)(n0 + j) * H + c4] = *(const float4*)&SI[j][c4];
    }
}

// ---------------------------------------------------------------------------
// k_gemm_dual_mfma (verified R10): hA = h@Wa + cbat[batch] (folded), hB = h@Wb;
// also zeroes agg[n0..n0+TE) (replaces the separate k_zero pass).
// ---------------------------------------------------------------------------
__global__ __launch_bounds__(256) void k_gemm_dual_mfma(
    const float* __restrict__ h,
    const u16* __restrict__ WaT, const u16* __restrict__ WbT,
    const float* __restrict__ cbatl, const int* __restrict__ batch,
    u16* __restrict__ Ca, u16* __restrict__ Cb, float* __restrict__ agg) {
    __shared__ u16 SI[TE][H + 8];
    __shared__ float CB[NB][H];
    __shared__ int bL[TE];
    const int t = threadIdx.x;
    const long long n0 = (long long)blockIdx.x * TE;
    const int w = t >> 6, l = t & 63;
    const int m16 = l & 15, g = l >> 4;
    const int row = w * 16 + m16;

    // zero this block's agg rows (independent of everything below)
    {
        const float4 z4 = make_float4(0.f, 0.f, 0.f, 0.f);
        for (int u = t; u < TE * H / 4; u += 256) {
            const int j = u >> 5, c4 = (u & 31) * 4;
            *(float4*)&agg[(size_t)(n0 + j) * H + c4] = z4;
        }
    }

    if (t < TE) {
        const long long n = n0 + t;
        bL[t] = batch[n < NN ? n : (NN - 1)];
    }
    for (int i = t; i < NB * H; i += 256) ((float*)CB)[i] = cbatl[i];

    bf16x8 afrag[4];
    {
        const float* hp = h + (size_t)(n0 + row) * H + g * 8;
#pragma unroll
        for (int ks = 0; ks < 4; ++ks) afrag[ks] = ld_f32_bf8(hp + ks * 32);
    }
    __syncthreads();   // bL / CB visible

    f32x4 accA[8], accB[8];
#pragma unroll
    for (int nt = 0; nt < 8; ++nt) {
#pragma unroll
        for (int j = 0; j < 4; ++j)
            accA[nt][j] = CB[bL[w * 16 + g * 4 + j]][nt * 16 + m16];
        accB[nt][0] = 0.f; accB[nt][1] = 0.f; accB[nt][2] = 0.f; accB[nt][3] = 0.f;
    }
#pragma unroll
    for (int ks = 0; ks < 4; ++ks) {
#pragma unroll
        for (int nt = 0; nt < 8; ++nt) {
            const size_t off = (size_t)(nt * 16 + m16) * H + ks * 32 + g * 8;
            const bf16x8 ba = *(const bf16x8*)&WaT[off];
            const bf16x8 bb = *(const bf16x8*)&WbT[off];
            accA[nt] = __builtin_amdgcn_mfma_f32_16x16x32_bf16(afrag[ks], ba, accA[nt], 0, 0, 0);
            accB[nt] = __builtin_amdgcn_mfma_f32_16x16x32_bf16(afrag[ks], bb, accB[nt], 0, 0, 0);
        }
    }

#pragma unroll
    for (int s = 0; s < 2; ++s) {
        __syncthreads();   // protect SI reuse across the two stores
#pragma unroll
        for (int nt = 0; nt < 8; ++nt)
#pragma unroll
            for (int j = 0; j < 4; ++j)
                SI[w * 16 + g * 4 + j][nt * 16 + m16] =
                    f2bf(s ? accB[nt][j] : accA[nt][j]);
        __syncthreads();
        u16* C = s ? Cb : Ca;
        for (int u = t; u < TE * 16; u += 256) {
            const int j = u >> 4, c8 = (u & 15) * 8;
            *(uint4*)&C[(size_t)(n0 + j) * H + c8] = *(const uint4*)&SI[j][c8];
        }
    }
}

// ---------------------------------------------------------------------------
// k_edge_mfma (R11): R9 zero-barrier structure (NO XCD swizzle — proven
// regression in R10) + DEEP-ISSUE gather staging: all 8 index pairs then all
// 16 hA/hB gathers are issued into registers before any unpack/pack work, so
// each wave keeps ~16 vector loads in flight (Little's-law MLP fix).
// ---------------------------------------------------------------------------
template <bool WRITE_E>
__global__ __launch_bounds__(256, 2) void k_edge_mfma(
    const u16* __restrict__ hA, const u16* __restrict__ hB,
    const u16* __restrict__ W1t, const u16* __restrict__ W2t,
    const float* __restrict__ b2,
    const int* __restrict__ rowS, const int* __restrict__ colS,
    u16* __restrict__ e, float* __restrict__ agg) {
    __shared__ u16 SI[TEE][H + 8];       // bf16; wave w owns rows [w*32,w*32+32)
    const int t = threadIdx.x;
    const long long e0 = (long long)blockIdx.x * TEE;
    const int w = t >> 6, l = t & 63;
    const int m16 = l & 15, g = l >> 4;

    // e A-fragments for both m-tiles — 8 x 16B, issued up front
    bf16x8 af0[4], af1[4];
    {
        const u16* ep0 = e + (size_t)(e0 + w * 32 + m16) * H + g * 8;
        const u16* ep1 = ep0 + 16 * H;
#pragma unroll
        for (int ks = 0; ks < 4; ++ks) {
            af0[ks] = *(const bf16x8*)(ep0 + ks * 32);
            af1[ks] = *(const bf16x8*)(ep1 + ks * 32);
        }
    }

    // wave-local stage with DEEP ISSUE: indices, then ALL 16 gathers into
    // registers, then unpack/pack/LDS-write.  Same-wave DS ordering; no
    // barrier (harness-verified pattern since R9).
    {
        int rj[8], cj[8];
#pragma unroll
        for (int it = 0; it < 8; ++it) {
            const int j = (l + it * 64) >> 4;
            rj[it] = rowS[e0 + w * 32 + j];
            cj[it] = colS[e0 + w * 32 + j];
        }
        uint4 ga[8], gb[8];
#pragma unroll
        for (int it = 0; it < 8; ++it) {
            const int c8 = ((l + it * 64) & 15) * 8;
            ga[it] = *(const uint4*)&hA[(size_t)rj[it] * H + c8];
            gb[it] = *(const uint4*)&hB[(size_t)cj[it] * H + c8];
        }
#pragma unroll
        for (int it = 0; it < 8; ++it) {
            const int u = l + it * 64;
            const int j = u >> 4, c8 = (u & 15) * 8;
            float va[8], vb[8], sm[8];
            unpack8(ga[it], va);
            unpack8(gb[it], vb);
#pragma unroll
            for (int q = 0; q < 8; ++q) sm[q] = va[q] + vb[q];
            *(uint4*)&SI[w * 32 + j][c8] = pack8(sm);
        }
    }

    // ---- GEMM1: acc = init + e @ W1c (B-frag shared across both m-tiles) ----
    f32x4 acc0[8], acc1[8];
#pragma unroll
    for (int nt = 0; nt < 8; ++nt) {
#pragma unroll
        for (int j = 0; j < 4; ++j) {
            acc0[nt][j] = bf2f(SI[w * 32 + g * 4 + j][nt * 16 + m16]);
            acc1[nt][j] = bf2f(SI[w * 32 + 16 + g * 4 + j][nt * 16 + m16]);
        }
    }
#pragma unroll
    for (int ks = 0; ks < 4; ++ks) {
#pragma unroll
        for (int nt = 0; nt < 8; ++nt) {
            const bf16x8 bfr =
                *(const bf16x8*)&W1t[(size_t)(nt * 16 + m16) * H + ks * 32 + g * 8];
            acc0[nt] = __builtin_amdgcn_mfma_f32_16x16x32_bf16(af0[ks], bfr, acc0[nt], 0, 0, 0);
            acc1[nt] = __builtin_amdgcn_mfma_f32_16x16x32_bf16(af1[ks], bfr, acc1[nt], 0, 0, 0);
        }
    }

    // hidden = relu -> SI (wave-own rows; same-wave DS ordering, no barrier)
#pragma unroll
    for (int nt = 0; nt < 8; ++nt)
#pragma unroll
        for (int j = 0; j < 4; ++j) {
            SI[w * 32 + g * 4 + j][nt * 16 + m16]      = f2bf(fmaxf(acc0[nt][j], 0.f));
            SI[w * 32 + 16 + g * 4 + j][nt * 16 + m16] = f2bf(fmaxf(acc1[nt][j], 0.f));
        }

    // ---- GEMM2: REUSE acc0/acc1 (re-init with b2) ----
#pragma unroll
    for (int nt = 0; nt < 8; ++nt) {
        const float bb = b2[nt * 16 + m16];
        acc0[nt][0] = bb; acc0[nt][1] = bb; acc0[nt][2] = bb; acc0[nt][3] = bb;
        acc1[nt][0] = bb; acc1[nt][1] = bb; acc1[nt][2] = bb; acc1[nt][3] = bb;
    }
#pragma unroll
    for (int ks = 0; ks < 4; ++ks) {
        const bf16x8 a20 = *(const bf16x8*)&SI[w * 32 + m16][ks * 32 + g * 8];
        const bf16x8 a21 = *(const bf16x8*)&SI[w * 32 + 16 + m16][ks * 32 + g * 8];
#pragma unroll
        for (int nt = 0; nt < 8; ++nt) {
            const bf16x8 bfr =
                *(const bf16x8*)&W2t[(size_t)(nt * 16 + m16) * H + ks * 32 + g * 8];
            acc0[nt] = __builtin_amdgcn_mfma_f32_16x16x32_bf16(a20, bfr, acc0[nt], 0, 0, 0);
            acc1[nt] = __builtin_amdgcn_mfma_f32_16x16x32_bf16(a21, bfr, acc1[nt], 0, 0, 0);
        }
    }

    // agg: f32 register atomics, one merge chain over the 8 sorted rows/lane
    {
        int r[8];
#pragma unroll
        for (int j = 0; j < 4; ++j) {
            r[j]     = rowS[e0 + w * 32 + g * 4 + j];
            r[4 + j] = rowS[e0 + w * 32 + 16 + g * 4 + j];
        }
#pragma unroll
        for (int nt = 0; nt < 8; ++nt) {
            const int c = nt * 16 + m16;
            float v[8];
#pragma unroll
            for (int j = 0; j < 4; ++j) { v[j] = acc0[nt][j]; v[4 + j] = acc1[nt][j]; }
            float s = v[0];
            int prev = r[0];
#pragma unroll
            for (int j = 1; j < 8; ++j) {
                if (r[j] == prev) s += v[j];
                else { atomicAdd(&agg[(size_t)prev * H + c], s); s = v[j]; prev = r[j]; }
            }
            atomicAdd(&agg[(size_t)prev * H + c], s);
        }
    }

    if (WRITE_E) {
        // stage output to wave-own SI rows, then wave-local packed stores
#pragma unroll
        for (int nt = 0; nt < 8; ++nt)
#pragma unroll
            for (int j = 0; j < 4; ++j) {
                SI[w * 32 + g * 4 + j][nt * 16 + m16]      = f2bf(acc0[nt][j]);
                SI[w * 32 + 16 + g * 4 + j][nt * 16 + m16] = f2bf(acc1[nt][j]);
            }
        // NO barrier: wave writes its own 32 edges
#pragma unroll
        for (int it = 0; it < 8; ++it) {
            const int u = l + it * 64;
            const int j = u >> 4, c8 = (u & 15) * 8;
            *(uint4*)&e[(size_t)(e0 + w * 32 + j) * H + c8] = *(const uint4*)&SI[w * 32 + j][c8];
        }
    }
}

// ---------------------------------------------------------------------------
// k_node_mfma (verified R10): zero barriers — wave-own SI rows, direct global
// nbat/batch reads, accumulator reuse across the two GEMM stages.
// h += relu(h@Wn1a + agg@Wn1b + nbat[batch]) @ Wn2 + bn2
// ---------------------------------------------------------------------------
__global__ __launch_bounds__(256) void k_node_mfma(
    const u16* __restrict__ Wn1aT, const u16* __restrict__ Wn1bT,
    const u16* __restrict__ Wn2T, const float* __restrict__ bn2,
    const float* __restrict__ nbatl, const int* __restrict__ batch,
    const float* __restrict__ agg, float* __restrict__ h) {
    __shared__ float SI[TE][H + 4];
    const int t = threadIdx.x;
    const long long n0 = (long long)blockIdx.x * TE;
    const int w = t >> 6, l = t & 63;
    const int m16 = l & 15, g = l >> 4;
    const int row = w * 16 + m16;

    bf16x8 afrag[4];
    {
        const float* hp = h + (size_t)(n0 + row) * H + g * 8;
#pragma unroll
        for (int ks = 0; ks < 4; ++ks) afrag[ks] = ld_f32_bf8(hp + ks * 32);
    }

    // batch for this lane's 4 fragment rows (direct global, L1-hot)
    int bj[4];
#pragma unroll
    for (int j = 0; j < 4; ++j) {
        const long long n = n0 + w * 16 + g * 4 + j;
        bj[j] = batch[n < NN ? n : (NN - 1)];
    }

    f32x4 acc[8];
#pragma unroll
    for (int nt = 0; nt < 8; ++nt)
#pragma unroll
        for (int j = 0; j < 4; ++j)
            acc[nt][j] = nbatl[(size_t)bj[j] * H + nt * 16 + m16];

#pragma unroll
    for (int ks = 0; ks < 4; ++ks)
#pragma unroll
        for (int nt = 0; nt < 8; ++nt) {
            const bf16x8 bfr =
                *(const bf16x8*)&Wn1aT[(size_t)(nt * 16 + m16) * H + ks * 32 + g * 8];
            acc[nt] = __builtin_amdgcn_mfma_f32_16x16x32_bf16(afrag[ks], bfr, acc[nt], 0, 0, 0);
        }

    {
        const float* ap = agg + (size_t)(n0 + row) * H + g * 8;
#pragma unroll
        for (int ks = 0; ks < 4; ++ks) afrag[ks] = ld_f32_bf8(ap + ks * 32);
    }
#pragma unroll
    for (int ks = 0; ks < 4; ++ks)
#pragma unroll
        for (int nt = 0; nt < 8; ++nt) {
            const bf16x8 bfr =
                *(const bf16x8*)&Wn1bT[(size_t)(nt * 16 + m16) * H + ks * 32 + g * 8];
            acc[nt] = __builtin_amdgcn_mfma_f32_16x16x32_bf16(afrag[ks], bfr, acc[nt], 0, 0, 0);
        }

    // hidden = relu(acc) -> wave-own SI rows (no barrier)
#pragma unroll
    for (int nt = 0; nt < 8; ++nt)
#pragma unroll
        for (int j = 0; j < 4; ++j)
            SI[w * 16 + g * 4 + j][nt * 16 + m16] = fmaxf(acc[nt][j], 0.f);

    // GEMM2: reuse acc (re-init with bn2); A-frags from wave-own SI rows
#pragma unroll
    for (int nt = 0; nt < 8; ++nt) {
        const float bb = bn2[nt * 16 + m16];
        acc[nt][0] = bb; acc[nt][1] = bb; acc[nt][2] = bb; acc[nt][3] = bb;
    }
#pragma unroll
    for (int ks = 0; ks < 4; ++ks) {
        bf16x8 a2;
        const float* hp = &SI[w * 16 + m16][ks * 32 + g * 8];
#pragma unroll
        for (int j = 0; j < 8; ++j) a2[j] = (short)f2bf(hp[j]);
#pragma unroll
        for (int nt = 0; nt < 8; ++nt) {
            const bf16x8 bfr =
                *(const bf16x8*)&Wn2T[(size_t)(nt * 16 + m16) * H + ks * 32 + g * 8];
            acc[nt] = __builtin_amdgcn_mfma_f32_16x16x32_bf16(a2, bfr, acc[nt], 0, 0, 0);
        }
    }

    // stage output to wave-own SI rows, then wave-local h += RMW
#pragma unroll
    for (int nt = 0; nt < 8; ++nt)
#pragma unroll
        for (int j = 0; j < 4; ++j)
            SI[w * 16 + g * 4 + j][nt * 16 + m16] = acc[nt][j];

#pragma unroll
    for (int it = 0; it < 8; ++it) {
        const int u = l + it * 64;            // u < 512
        const int j = u >> 5, c4 = (u & 31) * 4;
        float4 hv = *(const float4*)&h[(size_t)(n0 + w * 16 + j) * H + c4];
        const float4 sv = *(const float4*)&SI[w * 16 + j][c4];
        hv.x += sv.x; hv.y += sv.y; hv.z += sv.z; hv.w += sv.w;
        *(float4*)&h[(size_t)(n0 + w * 16 + j) * H + c4] = hv;
    }
}

// ---------------------------------------------------------------------------
// k_dec_mfma: decoder.  Layer 1 (H x H) via MFMA; 3-col layer 2 via VALU.
// ---------------------------------------------------------------------------
__global__ __launch_bounds__(256) void k_dec_mfma(
    const float* __restrict__ h,
    const u16* __restrict__ W1dt, const float* __restrict__ b1,
    const float* __restrict__ w2, const float* __restrict__ b2,
    float* __restrict__ out) {
    __shared__ float SI[TE][H + 4];
    const int t = threadIdx.x;
    const long long n0 = (long long)blockIdx.x * TE;
    const int w = t >> 6, l = t & 63;
    const int m16 = l & 15, g = l >> 4;
    const int row = w * 16 + m16;

    bf16x8 afrag[4];
    {
        const float* hp = h + (size_t)(n0 + row) * H + g * 8;
#pragma unroll
        for (int ks = 0; ks < 4; ++ks) afrag[ks] = ld_f32_bf8(hp + ks * 32);
    }

    f32x4 acc[8];
#pragma unroll
    for (int nt = 0; nt < 8; ++nt) {
        const float bb = b1[nt * 16 + m16];
        acc[nt][0] = bb; acc[nt][1] = bb; acc[nt][2] = bb; acc[nt][3] = bb;
    }
#pragma unroll
    for (int ks = 0; ks < 4; ++ks) {
#pragma unroll
        for (int nt = 0; nt < 8; ++nt) {
            const bf16x8 bfr =
                *(const bf16x8*)&W1dt[(size_t)(nt * 16 + m16) * H + ks * 32 + g * 8];
            acc[nt] = __builtin_amdgcn_mfma_f32_16x16x32_bf16(afrag[ks], bfr, acc[nt], 0, 0, 0);
        }
    }

    // hidden = relu -> SI
#pragma unroll
    for (int nt = 0; nt < 8; ++nt)
#pragma unroll
        for (int j = 0; j < 4; ++j)
            SI[w * 16 + g * 4 + j][nt * 16 + m16] = fmaxf(acc[nt][j], 0.f);
    __syncthreads();

    if (t < TE * 3) {
        const int n = t / 3, c = t - n * 3;
        if (n0 + n < NN) {
            float v = b2[c];
            for (int k = 0; k < H; ++k) v = fmaf(SI[n][k], w2[k * 3 + c], v);
            out[(size_t)(n0 + n) * 3 + c] = v;
        }
    }
}

// ---------------------------------------------------------------------------
extern "C" void kernel_launch(void* const* d_in, const int* in_sizes, int n_in,
                              void* d_out, int out_size, void* d_ws, size_t ws_size,
                              hipStream_t stream) {
    const float* x          = (const float*)d_in[0];
    const int*   edge_index = (const int*)d_in[1];
    const float* edge_attr  = (const float*)d_in[2];
    const float* cond       = (const float*)d_in[3];
    const int*   batch      = (const int*)d_in[4];
    const float* enc_node_w1 = (const float*)d_in[5];
    const float* enc_node_b1 = (const float*)d_in[6];
    const float* enc_node_w2 = (const float*)d_in[7];
    const float* enc_node_b2 = (const float*)d_in[8];
    const float* enc_edge_w1 = (const float*)d_in[9];
    const float* enc_edge_b1 = (const float*)d_in[10];
    const float* enc_edge_w2 = (const float*)d_in[11];
    const float* enc_edge_b2 = (const float*)d_in[12];
    const float* enc_cond_w1 = (const float*)d_in[13];
    const float* enc_cond_b1 = (const float*)d_in[14];
    const float* enc_cond_w2 = (const float*)d_in[15];
    const float* enc_cond_b2 = (const float*)d_in[16];
    const float* attn_wv = (const float*)d_in[17];
    const float* attn_bv = (const float*)d_in[18];
    const float* attn_wo = (const float*)d_in[19];
    const float* attn_bo = (const float*)d_in[20];
    const float* pe_w1 = (const float*)d_in[21];
    const float* pe_b1 = (const float*)d_in[22];
    const float* pe_w2 = (const float*)d_in[23];
    const float* pe_b2 = (const float*)d_in[24];
    const float* pn_w1 = (const float*)d_in[25];
    const float* pn_b1 = (const float*)d_in[26];
    const float* pn_w2 = (const float*)d_in[27];
    const float* pn_b2 = (const float*)d_in[28];
    const float* dec_w1 = (const float*)d_in[29];
    const float* dec_b1 = (const float*)d_in[30];
    const float* dec_w2 = (const float*)d_in[31];
    const float* dec_b2 = (const float*)d_in[32];

    // workspace (~250 MB): node arrays padded to NNP rows
    u16*   e    = (u16*)d_ws;                                  // NE*H bf16
    float* h    = (float*)((char*)d_ws + (size_t)NE * H * 2);  // NNP*H f32
    float* agg  = h + (size_t)NNP * H;                         // NNP*H f32
    u16*   hA   = (u16*)(agg + (size_t)NNP * H);               // NNP*H bf16
    u16*   hB   = hA + (size_t)NNP * H;                        // NNP*H bf16
    float* cbat = (float*)(hB + (size_t)NNP * H);              // NL*NB*H f32
    float* nbat = cbat + NL * NB * H;                          // NL*NB*H f32
    u16*   W1t   = (u16*)(nbat + NL * NB * H);                 // NL*H*H bf16 each:
    u16*   W2t   = W1t  + (size_t)NL * H * H;
    u16*   WaT   = W2t  + (size_t)NL * H * H;
    u16*   WbT   = WaT  + (size_t)NL * H * H;
    u16*   Wn1aT = WbT  + (size_t)NL * H * H;
    u16*   Wn1bT = Wn1aT + (size_t)NL * H * H;
    u16*   Wn2T  = Wn1bT + (size_t)NL * H * H;
    u16*   W2et  = Wn2T + (size_t)NL * H * H;                  // H*H bf16
    u16*   W2nt  = W2et + (size_t)H * H;                       // H*H bf16
    u16*   W1dt  = W2nt + (size_t)H * H;                       // H*H bf16
    u32*   cnt   = (u32*)(W1dt + (size_t)H * H);               // NNP u32
    int*   permS = (int*)(cnt + NNP);                          // NE int
    int*   rowS  = permS + NE;                                 // NE int (sorted rows)
    int*   colS  = rowS + NE;                                  // NE int (sorted cols)

    const int* rowi = edge_index;
    const int* coli = edge_index + NE;
    float* out = (float*)d_out;

    // ---- counting sort of edges by row (once per launch) ----
    k_zero<<<(NNP / 4 + 255) / 256, 256, 0, stream>>>((float*)cnt, NNP / 4);
    k_hist<<<NE / 256, 256, 0, stream>>>(rowi, cnt);
    k_scan<<<1, 1024, 0, stream>>>(cnt);
    k_scatter<<<NE / 256, 256, 0, stream>>>(rowi, coli, cnt, permS, rowS, colS);

    k_prep<<<dim3(NL, 8), 256, 0, stream>>>(pe_w1, pe_w2, pn_w1, pn_w2,
                                            enc_edge_w2, enc_node_w2, dec_w1,
                                            W1t, W2t, WaT, WbT,
                                            Wn1aT, Wn1bT, Wn2T, W2et, W2nt, W1dt);
    k_small<<<1, 128, 0, stream>>>(cond, enc_cond_w1, enc_cond_b1, enc_cond_w2, enc_cond_b2,
                                   attn_wv, attn_bv, attn_wo, attn_bo,
                                   pe_w1, pe_b1, pn_w1, pn_b1, cbat, nbat);
    k_enc_n_mfma<<<NNP / TE, 256, 0, stream>>>(
        x, enc_node_w1, enc_node_b1, W2nt, enc_node_b2, h);
    k_enc_e_mfma<<<NE / TE, 256, 0, stream>>>(
        edge_attr, permS, enc_edge_w1, enc_edge_b1, W2et, enc_edge_b2, e);

    for (int l = 0; l < NL; ++l) {
        k_gemm_dual_mfma<<<NNP / TE, 256, 0, stream>>>(
            h, WaT + (size_t)l * H * H, WbT + (size_t)l * H * H,
            cbat + l * NB * H, batch, hA, hB, agg);
        if (l < NL - 1)
            k_edge_mfma<true><<<NE / TEE, 256, 0, stream>>>(
                hA, hB, W1t + (size_t)l * H * H, W2t + (size_t)l * H * H,
                pe_b2 + l * H, rowS, colS, e, agg);
        else
            k_edge_mfma<false><<<NE / TEE, 256, 0, stream>>>(
                hA, hB, W1t + (size_t)l * H * H, W2t + (size_t)l * H * H,
                pe_b2 + l * H, rowS, colS, e, agg);
        k_node_mfma<<<NNP / TE, 256, 0, stream>>>(
            Wn1aT + (size_t)l * H * H, Wn1bT + (size_t)l * H * H,
            Wn2T + (size_t)l * H * H, pn_b2 + l * H,
            nbat + l * NB * H, batch, agg, h);
    }
    k_dec_mfma<<<NNP / TE, 256, 0, stream>>>(h, W1dt, dec_b1, dec_w2, dec_b2, out);
}

// Round 12
// 2303.898 us; speedup vs baseline: 1.0257x; 1.0002x over previous
//
#include <hip/hip_runtime.h>
#include <cstddef>

#define NN 50000
#define NNP 50048   // NN padded to multiple of TE (node arrays in workspace)
#define NE 640000
#define NB 4
#define H  128
#define NL 4
#define TE 64    // rows per block for node/enc MFMA kernels
#define TEE 128  // edges per block for k_edge_mfma (32 edges/wave x 4 waves)

typedef unsigned int u32;
typedef unsigned short u16;   // raw bf16 (intermediates only; I/O is fp32)
typedef __attribute__((ext_vector_type(8))) short bf16x8;
typedef __attribute__((ext_vector_type(4))) float f32x4;

__device__ __forceinline__ float bf2f(u16 s) {
    union { u32 u; float f; } v; v.u = ((u32)s) << 16; return v.f;
}
__device__ __forceinline__ u16 f2bf(float f) {
    union { float f; u32 u; } v; v.f = f;
    u32 u = v.u;
    u += 0x7FFF + ((u >> 16) & 1);   // RNE
    return (u16)(u >> 16);
}
__device__ __forceinline__ void unpack8(uint4 raw, float* d) {
    d[0] = bf2f(raw.x & 0xFFFF); d[1] = bf2f(raw.x >> 16);
    d[2] = bf2f(raw.y & 0xFFFF); d[3] = bf2f(raw.y >> 16);
    d[4] = bf2f(raw.z & 0xFFFF); d[5] = bf2f(raw.z >> 16);
    d[6] = bf2f(raw.w & 0xFFFF); d[7] = bf2f(raw.w >> 16);
}
__device__ __forceinline__ uint4 pack8(const float* s) {
    uint4 pk;
    pk.x = (u32)f2bf(s[0]) | ((u32)f2bf(s[1]) << 16);
    pk.y = (u32)f2bf(s[2]) | ((u32)f2bf(s[3]) << 16);
    pk.z = (u32)f2bf(s[4]) | ((u32)f2bf(s[5]) << 16);
    pk.w = (u32)f2bf(s[6]) | ((u32)f2bf(s[7]) << 16);
    return pk;
}
// fp32 row-slice (8 floats, 16B-aligned) -> bf16x8 A-fragment
__device__ __forceinline__ bf16x8 ld_f32_bf8(const float* __restrict__ p) {
    const float4 a = *(const float4*)p;
    const float4 b = *(const float4*)(p + 4);
    bf16x8 r;
    r[0] = (short)f2bf(a.x); r[1] = (short)f2bf(a.y);
    r[2] = (short)f2bf(a.z); r[3] = (short)f2bf(a.w);
    r[4] = (short)f2bf(b.x); r[5] = (short)f2bf(b.y);
    r[6] = (short)f2bf(b.z); r[7] = (short)f2bf(b.w);
    return r;
}

// ---------------------------------------------------------------------------
__global__ __launch_bounds__(256) void k_zero(float* __restrict__ p, int n4) {
    const int i = blockIdx.x * 256 + threadIdx.x;
    if (i < n4) ((float4*)p)[i] = make_float4(0.f, 0.f, 0.f, 0.f);
}

// ---------------------------------------------------------------------------
// Counting sort of edges by destination row.
// ---------------------------------------------------------------------------
__global__ __launch_bounds__(256) void k_hist(const int* __restrict__ rowi,
                                              u32* __restrict__ cnt) {
    const int i = blockIdx.x * 256 + threadIdx.x;
    if (i < NE) atomicAdd(&cnt[rowi[i]], 1u);
}

__global__ __launch_bounds__(1024) void k_scan(u32* __restrict__ cnt) {
    __shared__ u32 part[1024];
    const int t = threadIdx.x;
    const int CHUNK = (NN + 1023) / 1024;
    const int lo = t * CHUNK;
    const int hi = (lo + CHUNK < NN) ? lo + CHUNK : NN;
    u32 s = 0;
    for (int i = lo; i < hi; ++i) s += cnt[i];
    part[t] = s;
    __syncthreads();
    for (int ofs = 1; ofs < 1024; ofs <<= 1) {
        const u32 v = (t >= ofs) ? part[t - ofs] : 0u;
        __syncthreads();
        part[t] += v;
        __syncthreads();
    }
    u32 run = (t == 0) ? 0u : part[t - 1];   // exclusive prefix
    for (int i = lo; i < hi; ++i) { const u32 c = cnt[i]; cnt[i] = run; run += c; }
}

__global__ __launch_bounds__(256) void k_scatter(const int* __restrict__ rowi,
                                                 const int* __restrict__ coli,
                                                 u32* __restrict__ off,
                                                 int* __restrict__ permS,
                                                 int* __restrict__ rowS,
                                                 int* __restrict__ colS) {
    const int i = blockIdx.x * 256 + threadIdx.x;
    if (i < NE) {
        const int r = rowi[i];
        const u32 p = atomicAdd(&off[r], 1u);
        permS[p] = i; rowS[p] = r; colS[p] = coli[i];
    }
}

// ---------------------------------------------------------------------------
// k_prep: weights -> bf16, transposed to [n][k] for contiguous MFMA B-frags.
// ---------------------------------------------------------------------------
__global__ __launch_bounds__(256) void k_prep(
    const float* __restrict__ pe_w1, const float* __restrict__ pe_w2,
    const float* __restrict__ pn_w1, const float* __restrict__ pn_w2,
    const float* __restrict__ ew2,   const float* __restrict__ nw2,
    const float* __restrict__ dw1,
    u16* __restrict__ W1t, u16* __restrict__ W2t,
    u16* __restrict__ WaT, u16* __restrict__ WbT,
    u16* __restrict__ Wn1aT, u16* __restrict__ Wn1bT, u16* __restrict__ Wn2T,
    u16* __restrict__ W2et, u16* __restrict__ W2nt, u16* __restrict__ W1dt) {
    const int li = blockIdx.x;
    const float* src; u16* dst;
    switch (blockIdx.y) {
        case 0: src = pe_w1 + ((size_t)li * 512 + 256) * H; dst = W1t  + (size_t)li * H * H; break;
        case 1: src = pe_w2 + (size_t)li * H * H;           dst = W2t  + (size_t)li * H * H; break;
        case 2: src = pe_w1 + (size_t)li * 512 * H;         dst = WaT  + (size_t)li * H * H; break;
        case 3: src = pe_w1 + ((size_t)li * 512 + 128) * H; dst = WbT  + (size_t)li * H * H; break;
        case 4: src = pn_w1 + (size_t)li * 384 * H;         dst = Wn1aT + (size_t)li * H * H; break;
        case 5: src = pn_w1 + ((size_t)li * 384 + 128) * H; dst = Wn1bT + (size_t)li * H * H; break;
        case 6: src = pn_w2 + (size_t)li * H * H;           dst = Wn2T + (size_t)li * H * H; break;
        default:
            if (li == 0)      { src = ew2; dst = W2et; }
            else if (li == 1) { src = nw2; dst = W2nt; }
            else if (li == 2) { src = dw1; dst = W1dt; }
            else return;
            break;
    }
    for (int idx = threadIdx.x; idx < H * H; idx += 256) {
        const int n = idx >> 7, k = idx & 127;
        dst[idx] = f2bf(src[(size_t)k * H + n]);
    }
}

// ---------------------------------------------------------------------------
// k_small (verified R13): u, x_cond, per-layer consts cbat/nbat.
// ---------------------------------------------------------------------------
__global__ __launch_bounds__(128) void k_small(
    const float* __restrict__ cond,
    const float* __restrict__ ecw1, const float* __restrict__ ecb1,
    const float* __restrict__ ecw2, const float* __restrict__ ecb2,
    const float* __restrict__ wv, const float* __restrict__ bv,
    const float* __restrict__ wo, const float* __restrict__ bo,
    const float* __restrict__ pe_w1, const float* __restrict__ pe_b1,
    const float* __restrict__ pn_w1, const float* __restrict__ pn_b1,
    float* __restrict__ cbat, float* __restrict__ nbat) {
    __shared__ float tmp[NB][H];
    __shared__ float uL[NB][H];
    __shared__ float xcL[NB][H];
    const int t = threadIdx.x;
    for (int b = 0; b < NB; ++b) {
        float a = ecb1[t];
        for (int k = 0; k < 10; ++k) a = fmaf(cond[b * 10 + k], ecw1[k * H + t], a);
        tmp[b][t] = fmaxf(a, 0.f);
    }
    __syncthreads();
    for (int b = 0; b < NB; ++b) {
        float a = ecb2[t];
        for (int k = 0; k < H; ++k) a = fmaf(tmp[b][k], ecw2[k * H + t], a);
        uL[b][t] = a;
    }
    __syncthreads();
    for (int b = 0; b < NB; ++b) {
        float a = bv[t];
        for (int k = 0; k < H; ++k) a = fmaf(uL[b][k], wv[k * H + t], a);
        tmp[b][t] = a;
    }
    __syncthreads();
    for (int b = 0; b < NB; ++b) {
        float a = bo[t];
        for (int k = 0; k < H; ++k) a = fmaf(tmp[b][k], wo[k * H + t], a);
        xcL[b][t] = a;
    }
    __syncthreads();
    for (int l = 0; l < NL; ++l) {
        const float* w1u = pe_w1 + ((size_t)l * 512 + 384) * H;
        for (int b = 0; b < NB; ++b) {
            float a = pe_b1[l * H + t];
            for (int k = 0; k < H; ++k) a = fmaf(uL[b][k], w1u[k * H + t], a);
            cbat[(l * NB + b) * H + t] = a;
        }
        const float* w1x = pn_w1 + ((size_t)l * 384 + 256) * H;
        for (int b = 0; b < NB; ++b) {
            float a = pn_b1[l * H + t];
            for (int k = 0; k < H; ++k) a = fmaf(xcL[b][k], w1x[k * H + t], a);
            nbat[(l * NB + b) * H + t] = a;
        }
    }
}

// ---------------------------------------------------------------------------
// k_enc_e_mfma: edge encoder (verified R10): zero barriers, sorted e output.
// ---------------------------------------------------------------------------
__global__ __launch_bounds__(256) void k_enc_e_mfma(
    const float* __restrict__ ea,                         // [E,4]
    const int* __restrict__ permS,
    const float* __restrict__ w1, const float* __restrict__ b1,
    const u16* __restrict__ W2et, const float* __restrict__ b2,
    u16* __restrict__ e) {
    __shared__ float SI[TE][H + 4];
    const int t = threadIdx.x;
    const long long e0 = (long long)blockIdx.x * TE;
    const int w = t >> 6, l = t & 63;
    const int m16 = l & 15, g = l >> 4;
    const int row = w * 16 + m16;

    const int src = permS[e0 + row];
    const float4 av = *(const float4*)&ea[(size_t)src * 4];

    bf16x8 afrag[4];
#pragma unroll
    for (int ks = 0; ks < 4; ++ks) {
        const int c0 = ks * 32 + g * 8;
        float hv[8];
        {
            const float4 ba = *(const float4*)&b1[c0];
            const float4 bb = *(const float4*)&b1[c0 + 4];
            hv[0] = ba.x; hv[1] = ba.y; hv[2] = ba.z; hv[3] = ba.w;
            hv[4] = bb.x; hv[5] = bb.y; hv[6] = bb.z; hv[7] = bb.w;
        }
#pragma unroll
        for (int k = 0; k < 4; ++k) {
            const float s = (k == 0) ? av.x : (k == 1) ? av.y : (k == 2) ? av.z : av.w;
            const float4 wa = *(const float4*)&w1[k * H + c0];
            const float4 wb = *(const float4*)&w1[k * H + c0 + 4];
            hv[0] = fmaf(s, wa.x, hv[0]); hv[1] = fmaf(s, wa.y, hv[1]);
            hv[2] = fmaf(s, wa.z, hv[2]); hv[3] = fmaf(s, wa.w, hv[3]);
            hv[4] = fmaf(s, wb.x, hv[4]); hv[5] = fmaf(s, wb.y, hv[5]);
            hv[6] = fmaf(s, wb.z, hv[6]); hv[7] = fmaf(s, wb.w, hv[7]);
        }
#pragma unroll
        for (int j = 0; j < 8; ++j) afrag[ks][j] = (short)f2bf(fmaxf(hv[j], 0.f));
    }

    f32x4 acc[8];
#pragma unroll
    for (int nt = 0; nt < 8; ++nt) {
        const float bb = b2[nt * 16 + m16];
        acc[nt][0] = bb; acc[nt][1] = bb; acc[nt][2] = bb; acc[nt][3] = bb;
    }
#pragma unroll
    for (int ks = 0; ks < 4; ++ks) {
#pragma unroll
        for (int nt = 0; nt < 8; ++nt) {
            const bf16x8 bfr =
                *(const bf16x8*)&W2et[(size_t)(nt * 16 + m16) * H + ks * 32 + g * 8];
            acc[nt] = __builtin_amdgcn_mfma_f32_16x16x32_bf16(afrag[ks], bfr, acc[nt], 0, 0, 0);
        }
    }

#pragma unroll
    for (int nt = 0; nt < 8; ++nt)
#pragma unroll
        for (int j = 0; j < 4; ++j)
            SI[w * 16 + g * 4 + j][nt * 16 + m16] = acc[nt][j];
    // NO barrier: wave-own SI rows; wave-local packed stores.
#pragma unroll
    for (int it = 0; it < 4; ++it) {
        const int u = l + it * 64;            // u < 256
        const int j = u >> 4, c8 = (u & 15) * 8;
        *(uint4*)&e[(size_t)(e0 + w * 16 + j) * H + c8] = pack8(&SI[w * 16 + j][c8]);
    }
}

// ---------------------------------------------------------------------------
// k_enc_n_mfma: node encoder (verified R3).
// ---------------------------------------------------------------------------
__global__ __launch_bounds__(256) void k_enc_n_mfma(
    const float* __restrict__ x,                          // [N,12]
    const float* __restrict__ w1, const float* __restrict__ b1,
    const u16* __restrict__ W2nt, const float* __restrict__ b2,
    float* __restrict__ h) {
    __shared__ float SI[TE][H + 4];
    const int t = threadIdx.x;
    const long long n0 = (long long)blockIdx.x * TE;
    const int w = t >> 6, l = t & 63;
    const int m16 = l & 15, g = l >> 4;
    const int row = w * 16 + m16;
    const long long nr = (n0 + row < NN) ? (n0 + row) : (NN - 1);

    float av[12];
    {
        const float4 a0 = *(const float4*)&x[nr * 12];
        const float4 a1 = *(const float4*)&x[nr * 12 + 4];
        const float4 a2 = *(const float4*)&x[nr * 12 + 8];
        av[0] = a0.x; av[1] = a0.y; av[2] = a0.z; av[3] = a0.w;
        av[4] = a1.x; av[5] = a1.y; av[6] = a1.z; av[7] = a1.w;
        av[8] = a2.x; av[9] = a2.y; av[10] = a2.z; av[11] = a2.w;
    }

    bf16x8 afrag[4];
#pragma unroll
    for (int ks = 0; ks < 4; ++ks) {
        const int c0 = ks * 32 + g * 8;
        float hv[8];
        {
            const float4 ba = *(const float4*)&b1[c0];
            const float4 bb = *(const float4*)&b1[c0 + 4];
            hv[0] = ba.x; hv[1] = ba.y; hv[2] = ba.z; hv[3] = ba.w;
            hv[4] = bb.x; hv[5] = bb.y; hv[6] = bb.z; hv[7] = bb.w;
        }
#pragma unroll
        for (int k = 0; k < 12; ++k) {
            const float s = av[k];
            const float4 wa = *(const float4*)&w1[k * H + c0];
            const float4 wb = *(const float4*)&w1[k * H + c0 + 4];
            hv[0] = fmaf(s, wa.x, hv[0]); hv[1] = fmaf(s, wa.y, hv[1]);
            hv[2] = fmaf(s, wa.z, hv[2]); hv[3] = fmaf(s, wa.w, hv[3]);
            hv[4] = fmaf(s, wb.x, hv[4]); hv[5] = fmaf(s, wb.y, hv[5]);
            hv[6] = fmaf(s, wb.z, hv[6]); hv[7] = fmaf(s, wb.w, hv[7]);
        }
#pragma unroll
        for (int j = 0; j < 8; ++j) afrag[ks][j] = (short)f2bf(fmaxf(hv[j], 0.f));
    }

    f32x4 acc[8];
#pragma unroll
    for (int nt = 0; nt < 8; ++nt) {
        const float bb = b2[nt * 16 + m16];
        acc[nt][0] = bb; acc[nt][1] = bb; acc[nt][2] = bb; acc[nt][3] = bb;
    }
#pragma unroll
    for (int ks = 0; ks < 4; ++ks) {
#pragma unroll
        for (int nt = 0; nt < 8; ++nt) {
            const bf16x8 bfr =
                *(const bf16x8*)&W2nt[(size_t)(nt * 16 + m16) * H + ks * 32 + g * 8];
            acc[nt] = __builtin_amdgcn_mfma_f32_16x16x32_bf16(afrag[ks], bfr, acc[nt], 0, 0, 0);
        }
    }

#pragma unroll
    for (int nt = 0; nt < 8; ++nt)
#pragma unroll
        for (int j = 0; j < 4; ++j)
            SI[w * 16 + g * 4 + j][nt * 16 + m16] = acc[nt][j];
    __syncthreads();
    for (int u = t; u < TE * H / 4; u += 256) {
        const int j = u >> 5, c4 = (u & 31) * 4;
        *(float4*)&h[(size_t)(n0 + j) * H + c4] = *(const float4*)&SI[j][c4];
    }
}

// ---------------------------------------------------------------------------
// k_gemm_dual_mfma (verified R10, layer 0 only): hA = h@Wa + cbat[batch],
// hB = h@Wb; also zeroes agg rows.
// ---------------------------------------------------------------------------
__global__ __launch_bounds__(256) void k_gemm_dual_mfma(
    const float* __restrict__ h,
    const u16* __restrict__ WaT, const u16* __restrict__ WbT,
    const float* __restrict__ cbatl, const int* __restrict__ batch,
    u16* __restrict__ Ca, u16* __restrict__ Cb, float* __restrict__ agg) {
    __shared__ u16 SI[TE][H + 8];
    __shared__ float CB[NB][H];
    __shared__ int bL[TE];
    const int t = threadIdx.x;
    const long long n0 = (long long)blockIdx.x * TE;
    const int w = t >> 6, l = t & 63;
    const int m16 = l & 15, g = l >> 4;
    const int row = w * 16 + m16;

    {
        const float4 z4 = make_float4(0.f, 0.f, 0.f, 0.f);
        for (int u = t; u < TE * H / 4; u += 256) {
            const int j = u >> 5, c4 = (u & 31) * 4;
            *(float4*)&agg[(size_t)(n0 + j) * H + c4] = z4;
        }
    }

    if (t < TE) {
        const long long n = n0 + t;
        bL[t] = batch[n < NN ? n : (NN - 1)];
    }
    for (int i = t; i < NB * H; i += 256) ((float*)CB)[i] = cbatl[i];

    bf16x8 afrag[4];
    {
        const float* hp = h + (size_t)(n0 + row) * H + g * 8;
#pragma unroll
        for (int ks = 0; ks < 4; ++ks) afrag[ks] = ld_f32_bf8(hp + ks * 32);
    }
    __syncthreads();   // bL / CB visible

    f32x4 accA[8], accB[8];
#pragma unroll
    for (int nt = 0; nt < 8; ++nt) {
#pragma unroll
        for (int j = 0; j < 4; ++j)
            accA[nt][j] = CB[bL[w * 16 + g * 4 + j]][nt * 16 + m16];
        accB[nt][0] = 0.f; accB[nt][1] = 0.f; accB[nt][2] = 0.f; accB[nt][3] = 0.f;
    }
#pragma unroll
    for (int ks = 0; ks < 4; ++ks) {
#pragma unroll
        for (int nt = 0; nt < 8; ++nt) {
            const size_t off = (size_t)(nt * 16 + m16) * H + ks * 32 + g * 8;
            const bf16x8 ba = *(const bf16x8*)&WaT[off];
            const bf16x8 bb = *(const bf16x8*)&WbT[off];
            accA[nt] = __builtin_amdgcn_mfma_f32_16x16x32_bf16(afrag[ks], ba, accA[nt], 0, 0, 0);
            accB[nt] = __builtin_amdgcn_mfma_f32_16x16x32_bf16(afrag[ks], bb, accB[nt], 0, 0, 0);
        }
    }

#pragma unroll
    for (int s = 0; s < 2; ++s) {
        __syncthreads();   // protect SI reuse across the two stores
#pragma unroll
        for (int nt = 0; nt < 8; ++nt)
#pragma unroll
            for (int j = 0; j < 4; ++j)
                SI[w * 16 + g * 4 + j][nt * 16 + m16] =
                    f2bf(s ? accB[nt][j] : accA[nt][j]);
        __syncthreads();
        u16* C = s ? Cb : Ca;
        for (int u = t; u < TE * 16; u += 256) {
            const int j = u >> 4, c8 = (u & 15) * 8;
            *(uint4*)&C[(size_t)(n0 + j) * H + c8] = *(const uint4*)&SI[j][c8];
        }
    }
}

// ---------------------------------------------------------------------------
// k_edge_mfma (verified R11): zero barriers, 32 edges/wave, deep-issue gather.
// ---------------------------------------------------------------------------
template <bool WRITE_E>
__global__ __launch_bounds__(256, 2) void k_edge_mfma(
    const u16* __restrict__ hA, const u16* __restrict__ hB,
    const u16* __restrict__ W1t, const u16* __restrict__ W2t,
    const float* __restrict__ b2,
    const int* __restrict__ rowS, const int* __restrict__ colS,
    u16* __restrict__ e, float* __restrict__ agg) {
    __shared__ u16 SI[TEE][H + 8];       // bf16; wave w owns rows [w*32,w*32+32)
    const int t = threadIdx.x;
    const long long e0 = (long long)blockIdx.x * TEE;
    const int w = t >> 6, l = t & 63;
    const int m16 = l & 15, g = l >> 4;

    bf16x8 af0[4], af1[4];
    {
        const u16* ep0 = e + (size_t)(e0 + w * 32 + m16) * H + g * 8;
        const u16* ep1 = ep0 + 16 * H;
#pragma unroll
        for (int ks = 0; ks < 4; ++ks) {
            af0[ks] = *(const bf16x8*)(ep0 + ks * 32);
            af1[ks] = *(const bf16x8*)(ep1 + ks * 32);
        }
    }

    {
        int rj[8], cj[8];
#pragma unroll
        for (int it = 0; it < 8; ++it) {
            const int j = (l + it * 64) >> 4;
            rj[it] = rowS[e0 + w * 32 + j];
            cj[it] = colS[e0 + w * 32 + j];
        }
        uint4 ga[8], gb[8];
#pragma unroll
        for (int it = 0; it < 8; ++it) {
            const int c8 = ((l + it * 64) & 15) * 8;
            ga[it] = *(const uint4*)&hA[(size_t)rj[it] * H + c8];
            gb[it] = *(const uint4*)&hB[(size_t)cj[it] * H + c8];
        }
#pragma unroll
        for (int it = 0; it < 8; ++it) {
            const int u = l + it * 64;
            const int j = u >> 4, c8 = (u & 15) * 8;
            float va[8], vb[8], sm[8];
            unpack8(ga[it], va);
            unpack8(gb[it], vb);
#pragma unroll
            for (int q = 0; q < 8; ++q) sm[q] = va[q] + vb[q];
            *(uint4*)&SI[w * 32 + j][c8] = pack8(sm);
        }
    }

    f32x4 acc0[8], acc1[8];
#pragma unroll
    for (int nt = 0; nt < 8; ++nt) {
#pragma unroll
        for (int j = 0; j < 4; ++j) {
            acc0[nt][j] = bf2f(SI[w * 32 + g * 4 + j][nt * 16 + m16]);
            acc1[nt][j] = bf2f(SI[w * 32 + 16 + g * 4 + j][nt * 16 + m16]);
        }
    }
#pragma unroll
    for (int ks = 0; ks < 4; ++ks) {
#pragma unroll
        for (int nt = 0; nt < 8; ++nt) {
            const bf16x8 bfr =
                *(const bf16x8*)&W1t[(size_t)(nt * 16 + m16) * H + ks * 32 + g * 8];
            acc0[nt] = __builtin_amdgcn_mfma_f32_16x16x32_bf16(af0[ks], bfr, acc0[nt], 0, 0, 0);
            acc1[nt] = __builtin_amdgcn_mfma_f32_16x16x32_bf16(af1[ks], bfr, acc1[nt], 0, 0, 0);
        }
    }

#pragma unroll
    for (int nt = 0; nt < 8; ++nt)
#pragma unroll
        for (int j = 0; j < 4; ++j) {
            SI[w * 32 + g * 4 + j][nt * 16 + m16]      = f2bf(fmaxf(acc0[nt][j], 0.f));
            SI[w * 32 + 16 + g * 4 + j][nt * 16 + m16] = f2bf(fmaxf(acc1[nt][j], 0.f));
        }

#pragma unroll
    for (int nt = 0; nt < 8; ++nt) {
        const float bb = b2[nt * 16 + m16];
        acc0[nt][0] = bb; acc0[nt][1] = bb; acc0[nt][2] = bb; acc0[nt][3] = bb;
        acc1[nt][0] = bb; acc1[nt][1] = bb; acc1[nt][2] = bb; acc1[nt][3] = bb;
    }
#pragma unroll
    for (int ks = 0; ks < 4; ++ks) {
        const bf16x8 a20 = *(const bf16x8*)&SI[w * 32 + m16][ks * 32 + g * 8];
        const bf16x8 a21 = *(const bf16x8*)&SI[w * 32 + 16 + m16][ks * 32 + g * 8];
#pragma unroll
        for (int nt = 0; nt < 8; ++nt) {
            const bf16x8 bfr =
                *(const bf16x8*)&W2t[(size_t)(nt * 16 + m16) * H + ks * 32 + g * 8];
            acc0[nt] = __builtin_amdgcn_mfma_f32_16x16x32_bf16(a20, bfr, acc0[nt], 0, 0, 0);
            acc1[nt] = __builtin_amdgcn_mfma_f32_16x16x32_bf16(a21, bfr, acc1[nt], 0, 0, 0);
        }
    }

    {
        int r[8];
#pragma unroll
        for (int j = 0; j < 4; ++j) {
            r[j]     = rowS[e0 + w * 32 + g * 4 + j];
            r[4 + j] = rowS[e0 + w * 32 + 16 + g * 4 + j];
        }
#pragma unroll
        for (int nt = 0; nt < 8; ++nt) {
            const int c = nt * 16 + m16;
            float v[8];
#pragma unroll
            for (int j = 0; j < 4; ++j) { v[j] = acc0[nt][j]; v[4 + j] = acc1[nt][j]; }
            float s = v[0];
            int prev = r[0];
#pragma unroll
            for (int j = 1; j < 8; ++j) {
                if (r[j] == prev) s += v[j];
                else { atomicAdd(&agg[(size_t)prev * H + c], s); s = v[j]; prev = r[j]; }
            }
            atomicAdd(&agg[(size_t)prev * H + c], s);
        }
    }

    if (WRITE_E) {
#pragma unroll
        for (int nt = 0; nt < 8; ++nt)
#pragma unroll
            for (int j = 0; j < 4; ++j) {
                SI[w * 32 + g * 4 + j][nt * 16 + m16]      = f2bf(acc0[nt][j]);
                SI[w * 32 + 16 + g * 4 + j][nt * 16 + m16] = f2bf(acc1[nt][j]);
            }
#pragma unroll
        for (int it = 0; it < 8; ++it) {
            const int u = l + it * 64;
            const int j = u >> 4, c8 = (u & 15) * 8;
            *(uint4*)&e[(size_t)(e0 + w * 32 + j) * H + c8] = *(const uint4*)&SI[w * 32 + j][c8];
        }
    }
}

// ---------------------------------------------------------------------------
// Shared node-update body (verified R10 zero-barrier k_node): computes
// h_new = h + relu(h@Wn1a + agg@Wn1b + nbat[batch])@Wn2 + bn2, writes h,
// and leaves h_new (fp32) in wave-own SI rows.  bj[] returned for reuse.
// ---------------------------------------------------------------------------
__device__ __forceinline__ void node_update_body(
    float (*SI)[H + 4], const long long n0, const int t,
    const u16* __restrict__ Wn1aT, const u16* __restrict__ Wn1bT,
    const u16* __restrict__ Wn2T, const float* __restrict__ bn2,
    const float* __restrict__ nbatl, const int* __restrict__ batch,
    const float* __restrict__ agg, float* __restrict__ h, int bj[4]) {
    const int w = t >> 6, l = t & 63;
    const int m16 = l & 15, g = l >> 4;
    const int row = w * 16 + m16;

    bf16x8 afrag[4];
    {
        const float* hp = h + (size_t)(n0 + row) * H + g * 8;
#pragma unroll
        for (int ks = 0; ks < 4; ++ks) afrag[ks] = ld_f32_bf8(hp + ks * 32);
    }

#pragma unroll
    for (int j = 0; j < 4; ++j) {
        const long long n = n0 + w * 16 + g * 4 + j;
        bj[j] = batch[n < NN ? n : (NN - 1)];
    }

    f32x4 acc[8];
#pragma unroll
    for (int nt = 0; nt < 8; ++nt)
#pragma unroll
        for (int j = 0; j < 4; ++j)
            acc[nt][j] = nbatl[(size_t)bj[j] * H + nt * 16 + m16];

#pragma unroll
    for (int ks = 0; ks < 4; ++ks)
#pragma unroll
        for (int nt = 0; nt < 8; ++nt) {
            const bf16x8 bfr =
                *(const bf16x8*)&Wn1aT[(size_t)(nt * 16 + m16) * H + ks * 32 + g * 8];
            acc[nt] = __builtin_amdgcn_mfma_f32_16x16x32_bf16(afrag[ks], bfr, acc[nt], 0, 0, 0);
        }

    {
        const float* ap = agg + (size_t)(n0 + row) * H + g * 8;
#pragma unroll
        for (int ks = 0; ks < 4; ++ks) afrag[ks] = ld_f32_bf8(ap + ks * 32);
    }
#pragma unroll
    for (int ks = 0; ks < 4; ++ks)
#pragma unroll
        for (int nt = 0; nt < 8; ++nt) {
            const bf16x8 bfr =
                *(const bf16x8*)&Wn1bT[(size_t)(nt * 16 + m16) * H + ks * 32 + g * 8];
            acc[nt] = __builtin_amdgcn_mfma_f32_16x16x32_bf16(afrag[ks], bfr, acc[nt], 0, 0, 0);
        }

    // hidden = relu(acc) -> wave-own SI rows (no barrier)
#pragma unroll
    for (int nt = 0; nt < 8; ++nt)
#pragma unroll
        for (int j = 0; j < 4; ++j)
            SI[w * 16 + g * 4 + j][nt * 16 + m16] = fmaxf(acc[nt][j], 0.f);

    // GEMM2: reuse acc (re-init with bn2); A-frags from wave-own SI rows
#pragma unroll
    for (int nt = 0; nt < 8; ++nt) {
        const float bb = bn2[nt * 16 + m16];
        acc[nt][0] = bb; acc[nt][1] = bb; acc[nt][2] = bb; acc[nt][3] = bb;
    }
#pragma unroll
    for (int ks = 0; ks < 4; ++ks) {
        bf16x8 a2;
        const float* hp = &SI[w * 16 + m16][ks * 32 + g * 8];
#pragma unroll
        for (int j = 0; j < 8; ++j) a2[j] = (short)f2bf(hp[j]);
#pragma unroll
        for (int nt = 0; nt < 8; ++nt) {
            const bf16x8 bfr =
                *(const bf16x8*)&Wn2T[(size_t)(nt * 16 + m16) * H + ks * 32 + g * 8];
            acc[nt] = __builtin_amdgcn_mfma_f32_16x16x32_bf16(a2, bfr, acc[nt], 0, 0, 0);
        }
    }

    // stage update to wave-own SI rows, then wave-local h += RMW; keep h_new
    // (fp32) in SI for fused consumers.
#pragma unroll
    for (int nt = 0; nt < 8; ++nt)
#pragma unroll
        for (int j = 0; j < 4; ++j)
            SI[w * 16 + g * 4 + j][nt * 16 + m16] = acc[nt][j];

#pragma unroll
    for (int it = 0; it < 8; ++it) {
        const int u = l + it * 64;            // u < 512
        const int j = u >> 5, c4 = (u & 31) * 4;
        float4 hv = *(const float4*)&h[(size_t)(n0 + w * 16 + j) * H + c4];
        const float4 sv = *(const float4*)&SI[w * 16 + j][c4];
        hv.x += sv.x; hv.y += sv.y; hv.z += sv.z; hv.w += sv.w;
        *(float4*)&h[(size_t)(n0 + w * 16 + j) * H + c4] = hv;
        *(float4*)&SI[w * 16 + j][c4] = hv;   // h_new in LDS
    }
}

// ---------------------------------------------------------------------------
// k_node_next (R12): node update FUSED with next layer's hA/hB production and
// agg re-zero.  Zero barriers (wave-own rows throughout).
// ---------------------------------------------------------------------------
__global__ __launch_bounds__(256) void k_node_next(
    const u16* __restrict__ Wn1aT, const u16* __restrict__ Wn1bT,
    const u16* __restrict__ Wn2T, const float* __restrict__ bn2,
    const float* __restrict__ nbatl, const int* __restrict__ batch,
    float* __restrict__ agg, float* __restrict__ h,
    const u16* __restrict__ WaT2, const u16* __restrict__ WbT2,
    const float* __restrict__ cbat2,
    u16* __restrict__ Ca, u16* __restrict__ Cb) {
    __shared__ float SI[TE][H + 4];
    const int t = threadIdx.x;
    const long long n0 = (long long)blockIdx.x * TE;
    const int w = t >> 6, l = t & 63;
    const int m16 = l & 15, g = l >> 4;
    int bj[4];

    node_update_body(SI, n0, t, Wn1aT, Wn1bT, Wn2T, bn2, nbatl, batch, agg, h, bj);

    // A-frags of h_new from wave-own SI rows
    bf16x8 afn[4];
#pragma unroll
    for (int ks = 0; ks < 4; ++ks) {
        const float* hp = &SI[w * 16 + m16][ks * 32 + g * 8];
#pragma unroll
        for (int j = 0; j < 8; ++j) afn[ks][j] = (short)f2bf(hp[j]);
    }

    // zero this block's agg rows for the NEXT layer (only this block reads them)
    {
        const float4 z4 = make_float4(0.f, 0.f, 0.f, 0.f);
#pragma unroll
        for (int it = 0; it < 8; ++it) {
            const int u = l + it * 64;
            const int j = u >> 5, c4 = (u & 31) * 4;
            *(float4*)&agg[(size_t)(n0 + w * 16 + j) * H + c4] = z4;
        }
    }

    // hA = h_new @ Wa2 + cbat2[batch];  hB = h_new @ Wb2
    f32x4 aA[8], aB[8];
#pragma unroll
    for (int nt = 0; nt < 8; ++nt) {
#pragma unroll
        for (int j = 0; j < 4; ++j)
            aA[nt][j] = cbat2[(size_t)bj[j] * H + nt * 16 + m16];
        aB[nt][0] = 0.f; aB[nt][1] = 0.f; aB[nt][2] = 0.f; aB[nt][3] = 0.f;
    }
#pragma unroll
    for (int ks = 0; ks < 4; ++ks) {
#pragma unroll
        for (int nt = 0; nt < 8; ++nt) {
            const size_t off = (size_t)(nt * 16 + m16) * H + ks * 32 + g * 8;
            const bf16x8 ba = *(const bf16x8*)&WaT2[off];
            const bf16x8 bb = *(const bf16x8*)&WbT2[off];
            aA[nt] = __builtin_amdgcn_mfma_f32_16x16x32_bf16(afn[ks], ba, aA[nt], 0, 0, 0);
            aB[nt] = __builtin_amdgcn_mfma_f32_16x16x32_bf16(afn[ks], bb, aB[nt], 0, 0, 0);
        }
    }

    // stage bf16 via u16 view of SI (wave-own rows; same-wave DS ordering)
    u16* SIu = (u16*)&SI[0][0];
    const int RSU = 2 * (H + 4);   // u16 stride per row
#pragma unroll
    for (int s = 0; s < 2; ++s) {
#pragma unroll
        for (int nt = 0; nt < 8; ++nt)
#pragma unroll
            for (int j = 0; j < 4; ++j)
                SIu[(size_t)(w * 16 + g * 4 + j) * RSU + nt * 16 + m16] =
                    f2bf(s ? aB[nt][j] : aA[nt][j]);
        u16* C = s ? Cb : Ca;
#pragma unroll
        for (int it = 0; it < 4; ++it) {
            const int u = l + it * 64;        // u < 256
            const int j = u >> 4, c8 = (u & 15) * 8;
            *(uint4*)&C[(size_t)(n0 + w * 16 + j) * H + c8] =
                *(const uint4*)&SIu[(size_t)(w * 16 + j) * RSU + c8];
        }
    }
}

// ---------------------------------------------------------------------------
// k_node_last (R12): node update FUSED with the decoder.
// ---------------------------------------------------------------------------
__global__ __launch_bounds__(256) void k_node_last(
    const u16* __restrict__ Wn1aT, const u16* __restrict__ Wn1bT,
    const u16* __restrict__ Wn2T, const float* __restrict__ bn2,
    const float* __restrict__ nbatl, const int* __restrict__ batch,
    const float* __restrict__ agg, float* __restrict__ h,
    const u16* __restrict__ W1dt, const float* __restrict__ db1,
    const float* __restrict__ dw2, const float* __restrict__ db2,
    float* __restrict__ out) {
    __shared__ float SI[TE][H + 4];
    const int t = threadIdx.x;
    const long long n0 = (long long)blockIdx.x * TE;
    const int w = t >> 6, l = t & 63;
    const int m16 = l & 15, g = l >> 4;
    int bj[4];

    node_update_body(SI, n0, t, Wn1aT, Wn1bT, Wn2T, bn2, nbatl, batch, agg, h, bj);

    // decoder layer 1 on h_new (A-frags from wave-own SI rows)
    bf16x8 afn[4];
#pragma unroll
    for (int ks = 0; ks < 4; ++ks) {
        const float* hp = &SI[w * 16 + m16][ks * 32 + g * 8];
#pragma unroll
        for (int j = 0; j < 8; ++j) afn[ks][j] = (short)f2bf(hp[j]);
    }

    f32x4 ad[8];
#pragma unroll
    for (int nt = 0; nt < 8; ++nt) {
        const float bb = db1[nt * 16 + m16];
        ad[nt][0] = bb; ad[nt][1] = bb; ad[nt][2] = bb; ad[nt][3] = bb;
    }
#pragma unroll
    for (int ks = 0; ks < 4; ++ks) {
#pragma unroll
        for (int nt = 0; nt < 8; ++nt) {
            const bf16x8 bfr =
                *(const bf16x8*)&W1dt[(size_t)(nt * 16 + m16) * H + ks * 32 + g * 8];
            ad[nt] = __builtin_amdgcn_mfma_f32_16x16x32_bf16(afn[ks], bfr, ad[nt], 0, 0, 0);
        }
    }

    // hidden = relu -> SI (then cross-wave read needs one barrier)
#pragma unroll
    for (int nt = 0; nt < 8; ++nt)
#pragma unroll
        for (int j = 0; j < 4; ++j)
            SI[w * 16 + g * 4 + j][nt * 16 + m16] = fmaxf(ad[nt][j], 0.f);
    __syncthreads();

    if (t < TE * 3) {
        const int n = t / 3, c = t - n * 3;
        if (n0 + n < NN) {
            float v = db2[c];
            for (int k = 0; k < H; ++k) v = fmaf(SI[n][k], dw2[k * 3 + c], v);
            out[(size_t)(n0 + n) * 3 + c] = v;
        }
    }
}

// ---------------------------------------------------------------------------
extern "C" void kernel_launch(void* const* d_in, const int* in_sizes, int n_in,
                              void* d_out, int out_size, void* d_ws, size_t ws_size,
                              hipStream_t stream) {
    const float* x          = (const float*)d_in[0];
    const int*   edge_index = (const int*)d_in[1];
    const float* edge_attr  = (const float*)d_in[2];
    const float* cond       = (const float*)d_in[3];
    const int*   batch      = (const int*)d_in[4];
    const float* enc_node_w1 = (const float*)d_in[5];
    const float* enc_node_b1 = (const float*)d_in[6];
    const float* enc_node_w2 = (const float*)d_in[7];
    const float* enc_node_b2 = (const float*)d_in[8];
    const float* enc_edge_w1 = (const float*)d_in[9];
    const float* enc_edge_b1 = (const float*)d_in[10];
    const float* enc_edge_w2 = (const float*)d_in[11];
    const float* enc_edge_b2 = (const float*)d_in[12];
    const float* enc_cond_w1 = (const float*)d_in[13];
    const float* enc_cond_b1 = (const float*)d_in[14];
    const float* enc_cond_w2 = (const float*)d_in[15];
    const float* enc_cond_b2 = (const float*)d_in[16];
    const float* attn_wv = (const float*)d_in[17];
    const float* attn_bv = (const float*)d_in[18];
    const float* attn_wo = (const float*)d_in[19];
    const float* attn_bo = (const float*)d_in[20];
    const float* pe_w1 = (const float*)d_in[21];
    const float* pe_b1 = (const float*)d_in[22];
    const float* pe_w2 = (const float*)d_in[23];
    const float* pe_b2 = (const float*)d_in[24];
    const float* pn_w1 = (const float*)d_in[25];
    const float* pn_b1 = (const float*)d_in[26];
    const float* pn_w2 = (const float*)d_in[27];
    const float* pn_b2 = (const float*)d_in[28];
    const float* dec_w1 = (const float*)d_in[29];
    const float* dec_b1 = (const float*)d_in[30];
    const float* dec_w2 = (const float*)d_in[31];
    const float* dec_b2 = (const float*)d_in[32];

    // workspace (~250 MB): node arrays padded to NNP rows
    u16*   e    = (u16*)d_ws;                                  // NE*H bf16
    float* h    = (float*)((char*)d_ws + (size_t)NE * H * 2);  // NNP*H f32
    float* agg  = h + (size_t)NNP * H;                         // NNP*H f32
    u16*   hA   = (u16*)(agg + (size_t)NNP * H);               // NNP*H bf16
    u16*   hB   = hA + (size_t)NNP * H;                        // NNP*H bf16
    float* cbat = (float*)(hB + (size_t)NNP * H);              // NL*NB*H f32
    float* nbat = cbat + NL * NB * H;                          // NL*NB*H f32
    u16*   W1t   = (u16*)(nbat + NL * NB * H);                 // NL*H*H bf16 each:
    u16*   W2t   = W1t  + (size_t)NL * H * H;
    u16*   WaT   = W2t  + (size_t)NL * H * H;
    u16*   WbT   = WaT  + (size_t)NL * H * H;
    u16*   Wn1aT = WbT  + (size_t)NL * H * H;
    u16*   Wn1bT = Wn1aT + (size_t)NL * H * H;
    u16*   Wn2T  = Wn1bT + (size_t)NL * H * H;
    u16*   W2et  = Wn2T + (size_t)NL * H * H;                  // H*H bf16
    u16*   W2nt  = W2et + (size_t)H * H;                       // H*H bf16
    u16*   W1dt  = W2nt + (size_t)H * H;                       // H*H bf16
    u32*   cnt   = (u32*)(W1dt + (size_t)H * H);               // NNP u32
    int*   permS = (int*)(cnt + NNP);                          // NE int
    int*   rowS  = permS + NE;                                 // NE int (sorted rows)
    int*   colS  = rowS + NE;                                  // NE int (sorted cols)

    const int* rowi = edge_index;
    const int* coli = edge_index + NE;
    float* out = (float*)d_out;

    // ---- counting sort of edges by row (once per launch) ----
    k_zero<<<(NNP / 4 + 255) / 256, 256, 0, stream>>>((float*)cnt, NNP / 4);
    k_hist<<<NE / 256, 256, 0, stream>>>(rowi, cnt);
    k_scan<<<1, 1024, 0, stream>>>(cnt);
    k_scatter<<<NE / 256, 256, 0, stream>>>(rowi, coli, cnt, permS, rowS, colS);

    k_prep<<<dim3(NL, 8), 256, 0, stream>>>(pe_w1, pe_w2, pn_w1, pn_w2,
                                            enc_edge_w2, enc_node_w2, dec_w1,
                                            W1t, W2t, WaT, WbT,
                                            Wn1aT, Wn1bT, Wn2T, W2et, W2nt, W1dt);
    k_small<<<1, 128, 0, stream>>>(cond, enc_cond_w1, enc_cond_b1, enc_cond_w2, enc_cond_b2,
                                   attn_wv, attn_bv, attn_wo, attn_bo,
                                   pe_w1, pe_b1, pn_w1, pn_b1, cbat, nbat);
    k_enc_n_mfma<<<NNP / TE, 256, 0, stream>>>(
        x, enc_node_w1, enc_node_b1, W2nt, enc_node_b2, h);
    k_enc_e_mfma<<<NE / TE, 256, 0, stream>>>(
        edge_attr, permS, enc_edge_w1, enc_edge_b1, W2et, enc_edge_b2, e);

    // layer 0 hA/hB (+ agg zero)
    k_gemm_dual_mfma<<<NNP / TE, 256, 0, stream>>>(
        h, WaT, WbT, cbat, batch, hA, hB, agg);

    for (int l = 0; l < NL; ++l) {
        if (l < NL - 1) {
            k_edge_mfma<true><<<NE / TEE, 256, 0, stream>>>(
                hA, hB, W1t + (size_t)l * H * H, W2t + (size_t)l * H * H,
                pe_b2 + l * H, rowS, colS, e, agg);
            k_node_next<<<NNP / TE, 256, 0, stream>>>(
                Wn1aT + (size_t)l * H * H, Wn1bT + (size_t)l * H * H,
                Wn2T + (size_t)l * H * H, pn_b2 + l * H,
                nbat + l * NB * H, batch, agg, h,
                WaT + (size_t)(l + 1) * H * H, WbT + (size_t)(l + 1) * H * H,
                cbat + (l + 1) * NB * H, hA, hB);
        } else {
            k_edge_mfma<false><<<NE / TEE, 256, 0, stream>>>(
                hA, hB, W1t + (size_t)l * H * H, W2t + (size_t)l * H * H,
                pe_b2 + l * H, rowS, colS, e, agg);
            k_node_last<<<NNP / TE, 256, 0, stream>>>(
                Wn1aT + (size_t)l * H * H, Wn1bT + (size_t)l * H * H,
                Wn2T + (size_t)l * H * H, pn_b2 + l * H,
                nbat + l * NB * H, batch, agg, h,
                W1dt, dec_b1, dec_w2, dec_b2, out);
        }
    }
}